// Round 9
// baseline (331.572 us; speedup 1.0000x reference)
//
#include <hip/hip_runtime.h>
#include <hip/hip_bf16.h>

#define HEADS 12
#define DM    768
#define DKH   64
#define DFF   3072
#define BSZ   8
#define SEQ   512
#define MROWS (BSZ*SEQ)   // 4096
#define BH    (BSZ*HEADS) // 96

typedef __attribute__((ext_vector_type(8))) short bf16x8;
typedef __attribute__((ext_vector_type(4))) float f32x4;

__device__ __forceinline__ void gload_lds16(const ushort* g, ushort* l) {
  __builtin_amdgcn_global_load_lds(
      (const __attribute__((address_space(1))) unsigned int*)g,
      (__attribute__((address_space(3))) unsigned int*)l, 16, 0, 0);
}

__device__ __forceinline__ float b2f(ushort u) {
  union { unsigned int i; float f; } c; c.i = (unsigned int)u << 16; return c.f;
}

// ---------------- gb-writer device fn: 4 rows/block, 64 thr/row, 8 cols/thread ---------
__device__ __forceinline__ void gb_rows_256(
    int row, int t, const float* __restrict__ nsWS, const float* __restrict__ cumWS,
    const float* __restrict__ prior, float* __restrict__ gp, float* __restrict__ bp) {
  int bh = row >> 9, q = row & 511;
  const float* cum = cumWS + (size_t)bh*SEQ;
  const float* ns  = nsWS  + (size_t)bh*SEQ;
  float pr = prior[0];
  float c0 = pr + (1.f - pr)*0.01f;
  float cq = cum[q];
  size_t rb = ((size_t)bh*SEQ + q)*SEQ;
  int k0 = (t & 63)*8;
  float g8[8], b8[8];
  #pragma unroll
  for (int j = 0; j < 8; ++j) {
    int k = k0 + j;
    float g;
    if (k == q) g = c0;
    else {
      float c = cum[k];
      g = __expf((k > q) ? (c - cq) : (cq - c)) + 1e-4f;
    }
    float bb = c0;
    if (k == q+1)      bb = ns[q];
    else if (k+1 == q) bb = ns[q-1];
    g8[j] = g; b8[j] = bb;
  }
  *(float4*)(gp + rb + k0)     = *(float4*)&g8[0];
  *(float4*)(gp + rb + k0 + 4) = *(float4*)&g8[4];
  *(float4*)(bp + rb + k0)     = *(float4*)&b8[0];
  *(float4*)(bp + rb + k0 + 4) = *(float4*)&b8[4];
}

// ---------------- fused: dual pre-norm (both outputs bf16) + weight cvt ----------------
__global__ __launch_bounds__(256) void ln_cvt_kernel(
    const float* __restrict__ x,
    const float* __restrict__ g0, const float* __restrict__ b0, __hip_bfloat16* __restrict__ ln0,
    const float* __restrict__ gg, const float* __restrict__ gb, __hip_bfloat16* __restrict__ lnga,
    const float* __restrict__ swq, const float* __restrict__ swk, const float* __restrict__ swv,
    const float* __restrict__ w1s, const float* __restrict__ w2s,
    __hip_bfloat16* __restrict__ dqkv, __hip_bfloat16* __restrict__ d1,
    __hip_bfloat16* __restrict__ d2) {
  int t = threadIdx.x;
  if (blockIdx.x >= 1024) {
    long gid = (long)(blockIdx.x - 1024)*256 + t;
    long i = gid*4;
    const float* s; __hip_bfloat16* d; long off;
    if (i < 1769472L) {
      long j = i / 589824L; off = i - j*589824L;
      s = (j == 0) ? swq : (j == 1) ? swk : swv;
      d = dqkv + j*589824L;
    } else if (i < 4128768L) {
      off = i - 1769472L; s = w1s; d = d1;
    } else {
      off = i - 4128768L; s = w2s; d = d2;
    }
    float4 v = *(const float4*)(s + off);
    d[off+0] = __float2bfloat16(v.x);
    d[off+1] = __float2bfloat16(v.y);
    d[off+2] = __float2bfloat16(v.z);
    d[off+3] = __float2bfloat16(v.w);
    return;
  }
  int lane = t & 63, w = t >> 6;
  int row = blockIdx.x*4 + w;
  size_t base = (size_t)row * DM;
  float v[12]; float s = 0.f, s2 = 0.f;
  #pragma unroll
  for (int i = 0; i < 12; ++i) {
    v[i] = x[base + lane + 64*i];
    s += v[i]; s2 += v[i]*v[i];
  }
  #pragma unroll
  for (int off = 1; off < 64; off <<= 1) {
    s  += __shfl_xor(s,  off, 64);
    s2 += __shfl_xor(s2, off, 64);
  }
  float mean = s * (1.f/DM);
  float rstd = rsqrtf(s2 * (1.f/DM) - mean*mean + 1e-5f);
  #pragma unroll
  for (int i = 0; i < 12; ++i) {
    int c = lane + 64*i;
    float h = (v[i]-mean)*rstd;
    ln0[base + c]  = __float2bfloat16(h*g0[c] + b0[c]);
    lnga[base + c] = __float2bfloat16(h*gg[c] + gb[c]);
  }
}

// ---------------- tridiagonal softmax -> ns + prefix log-cumsum (wave scan) ------------
__global__ __launch_bounds__(512) void ga_edges_kernel(
    const float* __restrict__ Qg, const float* __restrict__ Kg,
    const float* __restrict__ prior, float* __restrict__ nsWS, float* __restrict__ cumWS) {
  __shared__ float pu[SEQ], pd[SEQ];
  __shared__ float wsum[8], wpre[8];
  int bh = blockIdx.x, m = threadIdx.x;
  const float* Qb = Qg + (size_t)bh*SEQ*DKH;
  const float* Kb = Kg + (size_t)bh*SEQ*DKH;
  const float4* qm = (const float4*)(Qb + (size_t)m*DKH);
  float su = -1e4f, sd = -1e4f;
  if (m < SEQ-1) {
    const float4* kn = (const float4*)(Kb + (size_t)(m+1)*DKH);
    float a = 0.f;
    #pragma unroll
    for (int i = 0; i < 16; ++i) {
      float4 q4 = qm[i], k4 = kn[i];
      a += q4.x*k4.x + q4.y*k4.y + q4.z*k4.z + q4.w*k4.w;
    }
    su = a * (1.f/DKH);
  }
  if (m >= 1) {
    const float4* kp = (const float4*)(Kb + (size_t)(m-1)*DKH);
    float a = 0.f;
    #pragma unroll
    for (int i = 0; i < 16; ++i) {
      float4 q4 = qm[i], k4 = kp[i];
      a += q4.x*k4.x + q4.y*k4.y + q4.z*k4.z + q4.w*k4.w;
    }
    sd = a * (1.f/DKH);
  }
  float mx = fmaxf(su, sd);
  float eu = __expf(su - mx), ed = __expf(sd - mx);
  float inv = 1.f / (eu + ed);
  pu[m] = eu * inv;
  pd[m] = ed * inv;
  __syncthreads();
  float pr = prior[0];
  float nsv = 0.f, lg = 0.f;
  if (m < SEQ-1) {
    float vv = sqrtf(pu[m]*pd[m+1] + 1e-4f);
    nsv = pr + (1.f - pr)*vv;
    lg = __logf(nsv + 1e-9f);
  }
  float v = lg;
  #pragma unroll
  for (int off = 1; off < 64; off <<= 1) {
    float u = __shfl_up(v, off, 64);
    if ((m & 63) >= off) v += u;
  }
  if ((m & 63) == 63) wsum[m >> 6] = v;
  __syncthreads();
  if (m == 0) {
    float a = 0.f;
    #pragma unroll
    for (int i = 0; i < 8; ++i) { wpre[i] = a; a += wsum[i]; }
  }
  __syncthreads();
  float incl = v + wpre[m >> 6];
  nsWS[(size_t)bh*SEQ + m] = nsv;
  cumWS[(size_t)bh*SEQ + m] = incl - lg;   // exclusive scan
}

// ---------------- 256x256 8-wave counted-vmcnt MFMA GEMM -------------------------------
// MODE 0: QKV: q/k cols -> qkv3; V cols -> transposed into vT. Blocks [144,240): GA proj.
// MODE 1: FFN1 (bias+relu), pure GEMM (192 blocks)
// MODE 2: FFN2 split-K x4 (192 blocks) + fused last-arriver reduce into out_x (gp)
template<int MODE>
__global__ __launch_bounds__(512, 2) void gemm256_kernel(
    const __hip_bfloat16* __restrict__ A, const __hip_bfloat16* __restrict__ B,
    const float* __restrict__ b0, const float* __restrict__ b1, const float* __restrict__ b2,
    __hip_bfloat16* __restrict__ C, __hip_bfloat16* __restrict__ vT,
    float* __restrict__ gp, int* __restrict__ cnt,
    const __hip_bfloat16* __restrict__ lnga,
    const float* __restrict__ gwq, const float* __restrict__ gbq,
    const float* __restrict__ gwk, const float* __restrict__ gbk,
    float* __restrict__ Qg, float* __restrict__ Kg) {
  constexpr int N    = (MODE==0) ? 2304 : (MODE==1) ? 3072 : 768;
  constexpr int TN   = N / 256;
  constexpr int LDAB = (MODE==2) ? 3072 : 768;
  constexpr int NT   = (MODE==0) ? 144 : 192;
  __shared__ ushort LDS[65536];          // 128 KB
  int t = threadIdx.x;
  int bidx = blockIdx.x;
  if (MODE == 0 && bidx >= NT) {
    // ---- GA q/k projection: 2 tasks (h, 256-row chunk) per block ----
    ushort* WQ = LDS;                  // [64][72]
    ushort* WK = LDS + 4608;
    for (int i = t; i < 4096; i += 512) {
      int d = i >> 6, c = i & 63;
      __hip_bfloat16 q = __float2bfloat16(gwq[i]);
      __hip_bfloat16 k = __float2bfloat16(gwk[i]);
      WQ[d*72 + c] = *(ushort*)&q;
      WK[d*72 + c] = *(ushort*)&k;
    }
    __syncthreads();
    int task = (bidx - 144)*2 + (t >> 8);
    int h  = task >> 4;
    int r0 = (task & 15) * 256;
    int t2 = t & 255;
    int lane = t2 & 63, w = t2 >> 6;
    int lrow = lane & 15, lhi = lane >> 4;
    const ushort* Ag2 = (const ushort*)lnga;
    bf16x8 a[4][2];
    #pragma unroll
    for (int i = 0; i < 4; ++i)
      #pragma unroll
      for (int ks = 0; ks < 2; ++ks)
        a[i][ks] = *(const bf16x8*)(Ag2 + (size_t)(r0 + w*64 + i*16 + lrow)*DM + h*64 + ks*32 + lhi*8);
    int b = r0 >> 9;
    #pragma unroll
    for (int qk = 0; qk < 2; ++qk) {
      const ushort* Wm = qk ? WK : WQ;
      const float* bias = qk ? gbk : gbq;
      float* Og = qk ? Kg : Qg;
      bf16x8 bf[4][2];
      #pragma unroll
      for (int j = 0; j < 4; ++j)
        #pragma unroll
        for (int ks = 0; ks < 2; ++ks)
          bf[j][ks] = *(const bf16x8*)&Wm[(j*16 + lrow)*72 + ks*32 + lhi*8];
      f32x4 acc[4][4] = {};
      #pragma unroll
      for (int i = 0; i < 4; ++i)
        #pragma unroll
        for (int j = 0; j < 4; ++j) {
          acc[i][j] = __builtin_amdgcn_mfma_f32_16x16x32_bf16(a[i][0], bf[j][0], acc[i][j], 0, 0, 0);
          acc[i][j] = __builtin_amdgcn_mfma_f32_16x16x32_bf16(a[i][1], bf[j][1], acc[i][j], 0, 0, 0);
        }
      #pragma unroll
      for (int i = 0; i < 4; ++i) {
        int rowb = r0 + w*64 + i*16 + lhi*4;
        #pragma unroll
        for (int j = 0; j < 4; ++j) {
          int d = j*16 + lrow;
          float bv = bias[d];
          #pragma unroll
          for (int r = 0; r < 4; ++r) {
            int sIdx = (rowb + r) & 511;
            Og[(((size_t)b*HEADS + h)*SEQ + sIdx)*DKH + d] = acc[i][j][r] + bv;
          }
        }
      }
    }
    return;
  }
  int lane = t & 63, w = t >> 6;
  int rin = lane >> 3, gr = lane & 7;
  int lrow = lane & 15, lhi = lane >> 4;
  int z = 0, tl = bidx;
  if (MODE == 2) { z = bidx / 48; tl = bidx % 48; }
  constexpr int NTIL = (MODE==2) ? 48 : NT;
  int tile = (tl & 7)*(NTIL/8) + (tl >> 3);     // XCD swizzle (NTIL % 8 == 0)
  int m0 = (tile / TN) * 256;
  int n0 = (tile % TN) * 256;
  int kOff = (MODE == 2) ? z * 768 : 0;
  __hip_bfloat16* Cbase = C;
  if (MODE == 2) C += (size_t)z * MROWS * 768;
  int wr = w >> 2, wc = w & 3;
  const ushort* Ag = (const ushort*)A;
  const ushort* Bg = (const ushort*)B;
  f32x4 acc[8][4] = {};
  // LDS content swizzle via pre-swizzled GLOBAL source (dest stays linear).
  auto STAGE = [&](int p, int kt) {
    int k0 = kOff + kt*64;
    ushort* Ad = &LDS[p*16384];
    ushort* Bd = &LDS[32768 + p*16384];
    int cs = (gr ^ rin) * 8;
    #pragma unroll
    for (int q = 0; q < 4; ++q) {
      int rr = q*64 + w*8 + rin;               // rr & 7 == rin
      gload_lds16(Ag + (size_t)(m0 + rr)*LDAB + k0 + cs, &Ad[(q*64 + w*8)*64]);
      gload_lds16(Bg + (size_t)(n0 + rr)*LDAB + k0 + cs, &Bd[(q*64 + w*8)*64]);
    }
  };
  const int nt = 12;                            // K = 768, BK = 64
  STAGE(0, 0);
  STAGE(1, 1);
  asm volatile("s_waitcnt vmcnt(8)" ::: "memory");   // tile 0 landed (tile 1 in flight)
  __builtin_amdgcn_s_barrier();
  int p = 0;
  for (int kt = 0; kt < nt; ++kt) {
    const ushort* Ar = &LDS[p*16384];
    const ushort* Br = &LDS[32768 + p*16384];
    int sw0 = (lhi ^ (lrow & 7)) * 8;           // ks=0: granule lhi
    int sw1 = ((4 + lhi) ^ (lrow & 7)) * 8;     // ks=1: granule 4+lhi
    bf16x8 a0[8], b0r[4], a1[8], b1r[4];
    #pragma unroll
    for (int i = 0; i < 8; ++i)
      a0[i] = *(const bf16x8*)&Ar[(wr*128 + i*16 + lrow)*64 + sw0];
    #pragma unroll
    for (int j = 0; j < 4; ++j)
      b0r[j] = *(const bf16x8*)&Br[(wc*64 + j*16 + lrow)*64 + sw0];
    #pragma unroll
    for (int i = 0; i < 8; ++i)
      #pragma unroll
      for (int j = 0; j < 4; ++j)
        acc[i][j] = __builtin_amdgcn_mfma_f32_16x16x32_bf16(a0[i], b0r[j], acc[i][j], 0, 0, 0);
    #pragma unroll
    for (int i = 0; i < 8; ++i)
      a1[i] = *(const bf16x8*)&Ar[(wr*128 + i*16 + lrow)*64 + sw1];
    #pragma unroll
    for (int j = 0; j < 4; ++j)
      b1r[j] = *(const bf16x8*)&Br[(wc*64 + j*16 + lrow)*64 + sw1];
    asm volatile("s_waitcnt lgkmcnt(0)" ::: "memory");  // all our LDS reads complete
    __builtin_amdgcn_sched_barrier(0);
    __builtin_amdgcn_s_barrier();               // every wave done reading buf p
    if (kt + 2 < nt) STAGE(p, kt + 2);          // safe: clobbers fully-consumed buffer
    __builtin_amdgcn_s_setprio(1);
    #pragma unroll
    for (int i = 0; i < 8; ++i)
      #pragma unroll
      for (int j = 0; j < 4; ++j)
        acc[i][j] = __builtin_amdgcn_mfma_f32_16x16x32_bf16(a1[i], b1r[j], acc[i][j], 0, 0, 0);
    __builtin_amdgcn_s_setprio(0);
    if (kt + 1 < nt) {
      if (kt + 2 < nt) asm volatile("s_waitcnt vmcnt(8)" ::: "memory");  // next tile landed
      else             asm volatile("s_waitcnt vmcnt(0)" ::: "memory");
      __builtin_amdgcn_s_barrier();
    }
    p ^= 1;
  }
  // ---- epilogue ----
  if (MODE == 0 && n0 >= 1536) {
    // V tile: bias + transpose via two-pass LDS bounce -> vT[bh][d][s]
    ushort* T = LDS;                      // [128][264] per pass
    int b = m0 >> 9, s0 = m0 & 511;
    #pragma unroll
    for (int ps = 0; ps < 2; ++ps) {
      if ((wc >> 1) == ps) {
        #pragma unroll
        for (int j = 0; j < 4; ++j) {
          int dl = (wc & 1)*64 + j*16 + lrow;
          float bvv = b2[n0 - 1536 + ps*128 + dl];
          #pragma unroll
          for (int i = 0; i < 8; ++i) {
            #pragma unroll
            for (int r = 0; r < 4; ++r) {
              __hip_bfloat16 hh = __float2bfloat16(acc[i][j][r] + bvv);
              T[dl*264 + wr*128 + i*16 + lhi*4 + r] = *(ushort*)&hh;
            }
          }
        }
      }
      __syncthreads();
      #pragma unroll
      for (int it = 0; it < 8; ++it) {
        int idx = t + 512*it;
        int dl = idx >> 5, sc8 = (idx & 31)*8;
        int dg = n0 - 1536 + ps*128 + dl;
        int h = dg >> 6, dmod = dg & 63;
        bf16x8 vv = *(const bf16x8*)&T[dl*264 + sc8];
        *(bf16x8*)((ushort*)vT + ((size_t)(b*HEADS + h)*64 + dmod)*512 + s0 + sc8) = vv;
      }
      __syncthreads();
    }
    return;
  }
  #pragma unroll
  for (int i = 0; i < 8; ++i) {
    int grow = m0 + wr*128 + i*16 + lhi*4;
    #pragma unroll
    for (int j = 0; j < 4; ++j) {
      int gcol = n0 + wc*64 + j*16 + lrow;
      float bvv;
      if (MODE == 0)      bvv = (gcol < 768) ? b0[gcol] : b1[gcol-768];
      else if (MODE == 1) bvv = b0[gcol];
      else                bvv = 0.f;
      #pragma unroll
      for (int r = 0; r < 4; ++r) {
        float v = acc[i][j][r] + bvv;
        if (MODE == 1) v = fmaxf(v, 0.f);
        C[(size_t)(grow + r)*N + gcol] = __float2bfloat16(v);
      }
    }
  }
  if (MODE == 2) {
    // last-arriver reduces the 4 partials (fixed z order -> deterministic)
    __shared__ int lastFlag;
    __threadfence();                 // release our partial stores (device scope)
    __syncthreads();                 // all threads' stores fenced
    if (t == 0) lastFlag = (atomicAdd(&cnt[tl], 1) == 3) ? 1 : 0;
    __syncthreads();
    if (lastFlag) {
      __threadfence();               // acquire: invalidate stale lines
      const ushort* pp = (const ushort*)Cbase;
      #pragma unroll
      for (int it = 0; it < 16; ++it) {
        int idx = it*512 + t;
        int rr = idx >> 5;
        int cc = (idx & 31) * 8;
        size_t gof = (size_t)(m0 + rr)*768 + n0 + cc;
        float a8[8];
        #pragma unroll
        for (int j = 0; j < 8; ++j) a8[j] = b0[n0 + cc + j];
        #pragma unroll
        for (int z2 = 0; z2 < 4; ++z2) {
          bf16x8 v = *(const bf16x8*)(pp + (size_t)z2*MROWS*768 + gof);
          #pragma unroll
          for (int j = 0; j < 8; ++j) a8[j] += b2f((ushort)v[j]);
        }
        float4 o0 = *(const float4*)(gp + gof);
        float4 o1 = *(const float4*)(gp + gof + 4);
        o0.x += a8[0]; o0.y += a8[1]; o0.z += a8[2]; o0.w += a8[3];
        o1.x += a8[4]; o1.y += a8[5]; o1.z += a8[6]; o1.w += a8[7];
        *(float4*)(gp + gof)     = o0;
        *(float4*)(gp + gof + 4) = o1;
      }
    }
  }
}

// ---------------- residual add + LN (wave-per-row) + gb-writer blocks ------------------
__global__ __launch_bounds__(256) void ln_res_kernel(
    const float* __restrict__ x, const __hip_bfloat16* __restrict__ a, float* __restrict__ xs,
    const float* __restrict__ g, const float* __restrict__ b, __hip_bfloat16* __restrict__ o,
    const float* __restrict__ nsWS, const float* __restrict__ cumWS,
    const float* __restrict__ prior, float* __restrict__ gp, float* __restrict__ bp) {
  int t = threadIdx.x;
  if (blockIdx.x >= 1024) {
    int row = 32768 + (blockIdx.x - 1024)*4 + (t >> 6);   // rows [32768, 49152)
    gb_rows_256(row, t, nsWS, cumWS, prior, gp, bp);
    return;
  }
  int lane = t & 63, w = t >> 6;
  int row = blockIdx.x*4 + w;
  size_t base = (size_t)row * DM;
  const ushort* ab = (const ushort*)a;
  float v[12]; float s = 0.f, s2 = 0.f;
  #pragma unroll
  for (int i = 0; i < 12; ++i) {
    int c = lane + 64*i;
    v[i] = x[base + c] + b2f(ab[base + c]);
    xs[base + c] = v[i];
    s += v[i]; s2 += v[i]*v[i];
  }
  #pragma unroll
  for (int off = 1; off < 64; off <<= 1) {
    s  += __shfl_xor(s,  off, 64);
    s2 += __shfl_xor(s2, off, 64);
  }
  float mean = s * (1.f/DM);
  float rstd = rsqrtf(s2 * (1.f/DM) - mean*mean + 1e-5f);
  #pragma unroll
  for (int i = 0; i < 12; ++i) {
    int c = lane + 64*i;
    o[base + c] = __float2bfloat16((v[i]-mean)*rstd*g[c] + b[c]);
  }
}

// ---------------- MFMA flash attention + gb-writer blocks ------------------------------
__global__ __launch_bounds__(256) void attn_mfma_kernel(
    const __hip_bfloat16* __restrict__ qk, const __hip_bfloat16* __restrict__ vT,
    const float* __restrict__ cumWS, const float* __restrict__ prior,
    __hip_bfloat16* __restrict__ att,
    const float* __restrict__ nsWS, float* __restrict__ gp, float* __restrict__ bp) {
  __shared__ ushort Ps[4][16][72];
  int t = threadIdx.x;
  int bidx = blockIdx.x;
  if (bidx >= 768) {
    int row = (bidx - 768)*4 + (t >> 6);   // rows [0, 32768)
    gb_rows_256(row, t, nsWS, cumWS, prior, gp, bp);
    return;
  }
  int lane = t & 63, wid = t >> 6;
  int tile = (bidx & 7)*96 + (bidx >> 3);
  int qt = tile & 7, bh = tile >> 3;
  int b = bh / HEADS, h = bh % HEADS;
  int lrow = lane & 15, lhi = lane >> 4;
  int qbase = qt*64 + wid*16;
  const ushort* qg = (const ushort*)qk;
  bf16x8 aq[2];
  {
    const ushort* qp = qg + (size_t)(b*SEQ + qbase + lrow)*2304 + h*64 + lhi*8;
    aq[0] = *(const bf16x8*)qp;
    aq[1] = *(const bf16x8*)(qp + 32);
  }
  const float* cum = cumWS + (size_t)bh*SEQ;
  float pr = prior[0];
  float c0 = pr + (1.f - pr)*0.01f;
  int qrow[4]; float cq[4];
  #pragma unroll
  for (int r = 0; r < 4; ++r) { qrow[r] = qbase + lhi*4 + r; cq[r] = cum[qrow[r]]; }
  float lsum[4] = {0.f, 0.f, 0.f, 0.f};
  f32x4 oacc[4] = {};
  const ushort* kg = qg + 768;
  const ushort* vg = (const ushort*)vT;
  for (int kt = 0; kt < 8; ++kt) {
    f32x4 sacc[4] = {};
    #pragma unroll
    for (int j = 0; j < 4; ++j) {
      const ushort* kp = kg + (size_t)(b*SEQ + kt*64 + j*16 + lrow)*2304 + h*64 + lhi*8;
      bf16x8 bk0 = *(const bf16x8*)kp;
      bf16x8 bk1 = *(const bf16x8*)(kp + 32);
      sacc[j] = __builtin_amdgcn_mfma_f32_16x16x32_bf16(aq[0], bk0, sacc[j], 0, 0, 0);
      sacc[j] = __builtin_amdgcn_mfma_f32_16x16x32_bf16(aq[1], bk1, sacc[j], 0, 0, 0);
    }
    float ck[4];
    #pragma unroll
    for (int j = 0; j < 4; ++j) ck[j] = cum[kt*64 + j*16 + lrow];
    #pragma unroll
    for (int j = 0; j < 4; ++j) {
      int kk = kt*64 + j*16 + lrow;
      #pragma unroll
      for (int r = 0; r < 4; ++r) {
        float e = __expf(fminf(sacc[j][r]*0.125f - 16.f, 60.f));
        lsum[r] += e;
        float dd = ck[j] - cq[r];
        float gpv = (kk == qrow[r]) ? c0 : (__expf((kk > qrow[r]) ? dd : -dd) + 1e-4f);
        __hip_bfloat16 pb = __float2bfloat16(e * gpv);
        Ps[wid][lhi*4 + r][j*16 + lrow] = *(ushort*)&pb;
      }
    }
    asm volatile("s_waitcnt lgkmcnt(0)" ::: "memory");
    __builtin_amdgcn_s_setprio(1);
    #pragma unroll
    for (int c = 0; c < 2; ++c) {
      bf16x8 ap = *(const bf16x8*)&Ps[wid][lrow][c*32 + lhi*8];
      #pragma unroll
      for (int dj = 0; dj < 4; ++dj) {
        const ushort* vp = vg + ((size_t)bh*64 + dj*16 + lrow)*512 + kt*64 + c*32 + lhi*8;
        bf16x8 bv = *(const bf16x8*)vp;
        oacc[dj] = __builtin_amdgcn_mfma_f32_16x16x32_bf16(ap, bv, oacc[dj], 0, 0, 0);
      }
    }
    __builtin_amdgcn_s_setprio(0);
  }
  #pragma unroll
  for (int off = 1; off < 16; off <<= 1) {
    #pragma unroll
    for (int r = 0; r < 4; ++r) lsum[r] += __shfl_xor(lsum[r], off, 64);
  }
  float inv[4];
  #pragma unroll
  for (int r = 0; r < 4; ++r) inv[r] = 1.f / lsum[r];
  #pragma unroll
  for (int dj = 0; dj < 4; ++dj) {
    #pragma unroll
    for (int r = 0; r < 4; ++r) {
      float v = oacc[dj][r] * inv[r];
      att[(size_t)(b*SEQ + qbase + lhi*4 + r)*DM + h*64 + dj*16 + lrow] = __float2bfloat16(v);
    }
  }
}

// ======================================================================================
extern "C" void kernel_launch(void* const* d_in, const int* in_sizes, int n_in,
                              void* d_out, int out_size, void* d_ws, size_t ws_size,
                              hipStream_t stream) {
  const float* x      = (const float*)d_in[0];
  const float* prior  = (const float*)d_in[2];
  const float* ga_g   = (const float*)d_in[3];
  const float* ga_b   = (const float*)d_in[4];
  const float* ga_wq  = (const float*)d_in[5];
  const float* ga_bq  = (const float*)d_in[6];
  const float* ga_wk  = (const float*)d_in[7];
  const float* ga_bk  = (const float*)d_in[8];
  const float* sa_wq  = (const float*)d_in[9];
  const float* sa_bq  = (const float*)d_in[10];
  const float* sa_wk  = (const float*)d_in[11];
  const float* sa_bk  = (const float*)d_in[12];
  const float* sa_wv  = (const float*)d_in[13];
  const float* sa_bv  = (const float*)d_in[14];
  const float* ff_w1  = (const float*)d_in[15];
  const float* ff_b1  = (const float*)d_in[16];
  const float* ff_w2  = (const float*)d_in[17];
  const float* ff_b2  = (const float*)d_in[18];
  const float* sl0_g  = (const float*)d_in[19];
  const float* sl0_b  = (const float*)d_in[20];
  const float* sl1_g  = (const float*)d_in[21];
  const float* sl1_b  = (const float*)d_in[22];

  float* out_x  = (float*)d_out;
  float* out_gp = out_x  + (size_t)MROWS*DM;
  float* out_bp = out_gp + (size_t)BH*SEQ*SEQ;

  char* W = (char*)d_ws;
  __hip_bfloat16* ln0    = (__hip_bfloat16*)(W + 0);          // 6.29 MB
  __hip_bfloat16* lnga   = (__hip_bfloat16*)(W + 6291456);    // 6.29 MB
  float* Qg   = (float*)(W + 12582912);                       // 12.58 MB
  float* Kg   = (float*)(W + 25165824);                       // 12.58 MB
  __hip_bfloat16* qkv3   = (__hip_bfloat16*)(W + 37748736);   // 18.87 MB [4096][2304]
  __hip_bfloat16* vT     = (__hip_bfloat16*)(W + 56623104);   // 6.29 MB
  __hip_bfloat16* attbuf = (__hip_bfloat16*)(W + 62914560);   // 6.29 MB
  __hip_bfloat16* ln1    = (__hip_bfloat16*)(W + 69206016);   // 6.29 MB
  __hip_bfloat16* wqkv   = (__hip_bfloat16*)(W + 75497472);   // 3.54 MB
  __hip_bfloat16* w1     = (__hip_bfloat16*)(W + 79036416);   // 4.72 MB
  __hip_bfloat16* w2     = (__hip_bfloat16*)(W + 83755008);   // 4.72 MB
  __hip_bfloat16* hbuf   = (__hip_bfloat16*)(W + 88473600);   // 25.17 MB [4096][3072]
  __hip_bfloat16* parts  = (__hip_bfloat16*)(W + 113639424);  // 25.17 MB (4 x 6.29)
  float* nsWS  = (float*)(W + 138805248);
  float* cumWS = (float*)(W + 139001856);
  int*   cnt   = (int*)  (W + 139198464);                     // 48 counters

  // 0. zero split-K counters (must happen every call; ws is not re-poisoned)
  hipMemsetAsync(cnt, 0, 48*sizeof(int), stream);
  // 1. dual pre-norm (both bf16) + weight conversions
  ln_cvt_kernel<<<7360, 256, 0, stream>>>(
      x, sl0_g, sl0_b, ln0, ga_g, ga_b, lnga,
      sa_wq, sa_wk, sa_wv, ff_w1, ff_w2, wqkv, w1, w2);
  // 2. QKV GEMM (V transposed in-epilogue) || GA q/k projection (role-split)
  gemm256_kernel<0><<<240, 512, 0, stream>>>(
      ln0, wqkv, sa_bq, sa_bk, sa_bv, qkv3, vT, nullptr, nullptr,
      lnga, ga_wq, ga_bq, ga_wk, ga_bk, Qg, Kg);
  // 3. tridiagonal softmax -> ns + cum
  ga_edges_kernel<<<BH, SEQ, 0, stream>>>(Qg, Kg, prior, nsWS, cumWS);
  // 4. flash attention + writer rows [0,32768)
  attn_mfma_kernel<<<768 + 8192, 256, 0, stream>>>(
      qkv3, vT, cumWS, prior, attbuf, nsWS, out_gp, out_bp);
  // 5. residual + pre-norm for FFN + writer rows [32768,49152)
  ln_res_kernel<<<1024 + 4096, 256, 0, stream>>>(
      x, attbuf, out_x, sl1_g, sl1_b, ln1,
      nsWS, cumWS, prior, out_gp, out_bp);
  // 6. FFN1 GEMM (pure)
  gemm256_kernel<1><<<192, 512, 0, stream>>>(
      ln1, w1, ff_b1, nullptr, nullptr, hbuf, nullptr, nullptr, nullptr,
      nullptr, nullptr, nullptr, nullptr, nullptr, nullptr, nullptr);
  // 7. FFN2 split-K x4 + fused last-arriver reduce into out_x
  gemm256_kernel<2><<<192, 512, 0, stream>>>(
      hbuf, w2, ff_b2, nullptr, nullptr, parts, nullptr, out_x, cnt,
      nullptr, nullptr, nullptr, nullptr, nullptr, nullptr, nullptr);
}

// Round 10
// 243.537 us; speedup vs baseline: 1.3615x; 1.3615x over previous
//
#include <hip/hip_runtime.h>
#include <hip/hip_bf16.h>

#define HEADS 12
#define DM    768
#define DKH   64
#define DFF   3072
#define BSZ   8
#define SEQ   512
#define MROWS (BSZ*SEQ)   // 4096
#define BH    (BSZ*HEADS) // 96

typedef __attribute__((ext_vector_type(8))) short bf16x8;
typedef __attribute__((ext_vector_type(4))) float f32x4;

__device__ __forceinline__ void gload_lds16(const ushort* g, ushort* l) {
  __builtin_amdgcn_global_load_lds(
      (const __attribute__((address_space(1))) unsigned int*)g,
      (__attribute__((address_space(3))) unsigned int*)l, 16, 0, 0);
}

__device__ __forceinline__ float b2f(ushort u) {
  union { unsigned int i; float f; } c; c.i = (unsigned int)u << 16; return c.f;
}

// ---------------- gb-writer device fn: 4 rows/block, 64 thr/row, 8 cols/thread ---------
__device__ __forceinline__ void gb_rows_256(
    int row, int t, const float* __restrict__ nsWS, const float* __restrict__ cumWS,
    const float* __restrict__ prior, float* __restrict__ gp, float* __restrict__ bp) {
  int bh = row >> 9, q = row & 511;
  const float* cum = cumWS + (size_t)bh*SEQ;
  const float* ns  = nsWS  + (size_t)bh*SEQ;
  float pr = prior[0];
  float c0 = pr + (1.f - pr)*0.01f;
  float cq = cum[q];
  size_t rb = ((size_t)bh*SEQ + q)*SEQ;
  int k0 = (t & 63)*8;
  float g8[8], b8[8];
  #pragma unroll
  for (int j = 0; j < 8; ++j) {
    int k = k0 + j;
    float g;
    if (k == q) g = c0;
    else {
      float c = cum[k];
      g = __expf((k > q) ? (c - cq) : (cq - c)) + 1e-4f;
    }
    float bb = c0;
    if (k == q+1)      bb = ns[q];
    else if (k+1 == q) bb = ns[q-1];
    g8[j] = g; b8[j] = bb;
  }
  *(float4*)(gp + rb + k0)     = *(float4*)&g8[0];
  *(float4*)(gp + rb + k0 + 4) = *(float4*)&g8[4];
  *(float4*)(bp + rb + k0)     = *(float4*)&b8[0];
  *(float4*)(bp + rb + k0 + 4) = *(float4*)&b8[4];
}

// ---------------- fused: dual pre-norm (both outputs bf16) + weight cvt ----------------
__global__ __launch_bounds__(256) void ln_cvt_kernel(
    const float* __restrict__ x,
    const float* __restrict__ g0, const float* __restrict__ b0, __hip_bfloat16* __restrict__ ln0,
    const float* __restrict__ gg, const float* __restrict__ gb, __hip_bfloat16* __restrict__ lnga,
    const float* __restrict__ swq, const float* __restrict__ swk, const float* __restrict__ swv,
    const float* __restrict__ w1s, const float* __restrict__ w2s,
    __hip_bfloat16* __restrict__ dqkv, __hip_bfloat16* __restrict__ d1,
    __hip_bfloat16* __restrict__ d2) {
  int t = threadIdx.x;
  if (blockIdx.x >= 1024) {
    long gid = (long)(blockIdx.x - 1024)*256 + t;
    long i = gid*4;
    const float* s; __hip_bfloat16* d; long off;
    if (i < 1769472L) {
      long j = i / 589824L; off = i - j*589824L;
      s = (j == 0) ? swq : (j == 1) ? swk : swv;
      d = dqkv + j*589824L;
    } else if (i < 4128768L) {
      off = i - 1769472L; s = w1s; d = d1;
    } else {
      off = i - 4128768L; s = w2s; d = d2;
    }
    float4 v = *(const float4*)(s + off);
    d[off+0] = __float2bfloat16(v.x);
    d[off+1] = __float2bfloat16(v.y);
    d[off+2] = __float2bfloat16(v.z);
    d[off+3] = __float2bfloat16(v.w);
    return;
  }
  int lane = t & 63, w = t >> 6;
  int row = blockIdx.x*4 + w;
  size_t base = (size_t)row * DM;
  float v[12]; float s = 0.f, s2 = 0.f;
  #pragma unroll
  for (int i = 0; i < 12; ++i) {
    v[i] = x[base + lane + 64*i];
    s += v[i]; s2 += v[i]*v[i];
  }
  #pragma unroll
  for (int off = 1; off < 64; off <<= 1) {
    s  += __shfl_xor(s,  off, 64);
    s2 += __shfl_xor(s2, off, 64);
  }
  float mean = s * (1.f/DM);
  float rstd = rsqrtf(s2 * (1.f/DM) - mean*mean + 1e-5f);
  #pragma unroll
  for (int i = 0; i < 12; ++i) {
    int c = lane + 64*i;
    float h = (v[i]-mean)*rstd;
    ln0[base + c]  = __float2bfloat16(h*g0[c] + b0[c]);
    lnga[base + c] = __float2bfloat16(h*gg[c] + gb[c]);
  }
}

// ---------------- tridiagonal softmax -> ns + prefix log-cumsum (wave scan) ------------
__global__ __launch_bounds__(512) void ga_edges_kernel(
    const float* __restrict__ Qg, const float* __restrict__ Kg,
    const float* __restrict__ prior, float* __restrict__ nsWS, float* __restrict__ cumWS) {
  __shared__ float pu[SEQ], pd[SEQ];
  __shared__ float wsum[8], wpre[8];
  int bh = blockIdx.x, m = threadIdx.x;
  const float* Qb = Qg + (size_t)bh*SEQ*DKH;
  const float* Kb = Kg + (size_t)bh*SEQ*DKH;
  const float4* qm = (const float4*)(Qb + (size_t)m*DKH);
  float su = -1e4f, sd = -1e4f;
  if (m < SEQ-1) {
    const float4* kn = (const float4*)(Kb + (size_t)(m+1)*DKH);
    float a = 0.f;
    #pragma unroll
    for (int i = 0; i < 16; ++i) {
      float4 q4 = qm[i], k4 = kn[i];
      a += q4.x*k4.x + q4.y*k4.y + q4.z*k4.z + q4.w*k4.w;
    }
    su = a * (1.f/DKH);
  }
  if (m >= 1) {
    const float4* kp = (const float4*)(Kb + (size_t)(m-1)*DKH);
    float a = 0.f;
    #pragma unroll
    for (int i = 0; i < 16; ++i) {
      float4 q4 = qm[i], k4 = kp[i];
      a += q4.x*k4.x + q4.y*k4.y + q4.z*k4.z + q4.w*k4.w;
    }
    sd = a * (1.f/DKH);
  }
  float mx = fmaxf(su, sd);
  float eu = __expf(su - mx), ed = __expf(sd - mx);
  float inv = 1.f / (eu + ed);
  pu[m] = eu * inv;
  pd[m] = ed * inv;
  __syncthreads();
  float pr = prior[0];
  float nsv = 0.f, lg = 0.f;
  if (m < SEQ-1) {
    float vv = sqrtf(pu[m]*pd[m+1] + 1e-4f);
    nsv = pr + (1.f - pr)*vv;
    lg = __logf(nsv + 1e-9f);
  }
  float v = lg;
  #pragma unroll
  for (int off = 1; off < 64; off <<= 1) {
    float u = __shfl_up(v, off, 64);
    if ((m & 63) >= off) v += u;
  }
  if ((m & 63) == 63) wsum[m >> 6] = v;
  __syncthreads();
  if (m == 0) {
    float a = 0.f;
    #pragma unroll
    for (int i = 0; i < 8; ++i) { wpre[i] = a; a += wsum[i]; }
  }
  __syncthreads();
  float incl = v + wpre[m >> 6];
  nsWS[(size_t)bh*SEQ + m] = nsv;
  cumWS[(size_t)bh*SEQ + m] = incl - lg;   // exclusive scan
}

// ---------------- 256x256 8-wave counted-vmcnt MFMA GEMM -------------------------------
// MODE 0: QKV: q/k cols -> qkv3; V cols -> transposed into vT. Blocks [144,240): GA proj.
// MODE 1: FFN1 (bias+relu), pure GEMM (192 blocks)
// MODE 2: FFN2 split-K x4 (192 blocks), bf16 partials (separate reduce kernel)
template<int MODE>
__global__ __launch_bounds__(512, 2) void gemm256_kernel(
    const __hip_bfloat16* __restrict__ A, const __hip_bfloat16* __restrict__ B,
    const float* __restrict__ b0, const float* __restrict__ b1, const float* __restrict__ b2,
    __hip_bfloat16* __restrict__ C, __hip_bfloat16* __restrict__ vT,
    const __hip_bfloat16* __restrict__ lnga,
    const float* __restrict__ gwq, const float* __restrict__ gbq,
    const float* __restrict__ gwk, const float* __restrict__ gbk,
    float* __restrict__ Qg, float* __restrict__ Kg) {
  constexpr int N    = (MODE==0) ? 2304 : (MODE==1) ? 3072 : 768;
  constexpr int TN   = N / 256;
  constexpr int LDAB = (MODE==2) ? 3072 : 768;
  constexpr int NT   = (MODE==0) ? 144 : 192;
  __shared__ ushort LDS[65536];          // 128 KB
  int t = threadIdx.x;
  int bidx = blockIdx.x;
  if (MODE == 0 && bidx >= NT) {
    // ---- GA q/k projection: 2 tasks (h, 256-row chunk) per block ----
    ushort* WQ = LDS;                  // [64][72]
    ushort* WK = LDS + 4608;
    for (int i = t; i < 4096; i += 512) {
      int d = i >> 6, c = i & 63;
      __hip_bfloat16 q = __float2bfloat16(gwq[i]);
      __hip_bfloat16 k = __float2bfloat16(gwk[i]);
      WQ[d*72 + c] = *(ushort*)&q;
      WK[d*72 + c] = *(ushort*)&k;
    }
    __syncthreads();
    int task = (bidx - 144)*2 + (t >> 8);
    int h  = task >> 4;
    int r0 = (task & 15) * 256;
    int t2 = t & 255;
    int lane = t2 & 63, w = t2 >> 6;
    int lrow = lane & 15, lhi = lane >> 4;
    const ushort* Ag2 = (const ushort*)lnga;
    bf16x8 a[4][2];
    #pragma unroll
    for (int i = 0; i < 4; ++i)
      #pragma unroll
      for (int ks = 0; ks < 2; ++ks)
        a[i][ks] = *(const bf16x8*)(Ag2 + (size_t)(r0 + w*64 + i*16 + lrow)*DM + h*64 + ks*32 + lhi*8);
    int b = r0 >> 9;
    #pragma unroll
    for (int qk = 0; qk < 2; ++qk) {
      const ushort* Wm = qk ? WK : WQ;
      const float* bias = qk ? gbk : gbq;
      float* Og = qk ? Kg : Qg;
      bf16x8 bf[4][2];
      #pragma unroll
      for (int j = 0; j < 4; ++j)
        #pragma unroll
        for (int ks = 0; ks < 2; ++ks)
          bf[j][ks] = *(const bf16x8*)&Wm[(j*16 + lrow)*72 + ks*32 + lhi*8];
      f32x4 acc[4][4] = {};
      #pragma unroll
      for (int i = 0; i < 4; ++i)
        #pragma unroll
        for (int j = 0; j < 4; ++j) {
          acc[i][j] = __builtin_amdgcn_mfma_f32_16x16x32_bf16(a[i][0], bf[j][0], acc[i][j], 0, 0, 0);
          acc[i][j] = __builtin_amdgcn_mfma_f32_16x16x32_bf16(a[i][1], bf[j][1], acc[i][j], 0, 0, 0);
        }
      #pragma unroll
      for (int i = 0; i < 4; ++i) {
        int rowb = r0 + w*64 + i*16 + lhi*4;
        #pragma unroll
        for (int j = 0; j < 4; ++j) {
          int d = j*16 + lrow;
          float bv = bias[d];
          #pragma unroll
          for (int r = 0; r < 4; ++r) {
            int sIdx = (rowb + r) & 511;
            Og[(((size_t)b*HEADS + h)*SEQ + sIdx)*DKH + d] = acc[i][j][r] + bv;
          }
        }
      }
    }
    return;
  }
  int lane = t & 63, w = t >> 6;
  int rin = lane >> 3, gr = lane & 7;
  int lrow = lane & 15, lhi = lane >> 4;
  int z = 0, tl = bidx;
  if (MODE == 2) { z = bidx / 48; tl = bidx % 48; }
  constexpr int NTIL = (MODE==2) ? 48 : NT;
  int tile = (tl & 7)*(NTIL/8) + (tl >> 3);     // XCD swizzle (NTIL % 8 == 0)
  int m0 = (tile / TN) * 256;
  int n0 = (tile % TN) * 256;
  int kOff = (MODE == 2) ? z * 768 : 0;
  if (MODE == 2) C += (size_t)z * MROWS * 768;
  int wr = w >> 2, wc = w & 3;
  const ushort* Ag = (const ushort*)A;
  const ushort* Bg = (const ushort*)B;
  f32x4 acc[8][4] = {};
  // LDS content swizzle via pre-swizzled GLOBAL source (dest stays linear).
  auto STAGE = [&](int p, int kt) {
    int k0 = kOff + kt*64;
    ushort* Ad = &LDS[p*16384];
    ushort* Bd = &LDS[32768 + p*16384];
    int cs = (gr ^ rin) * 8;
    #pragma unroll
    for (int q = 0; q < 4; ++q) {
      int rr = q*64 + w*8 + rin;               // rr & 7 == rin
      gload_lds16(Ag + (size_t)(m0 + rr)*LDAB + k0 + cs, &Ad[(q*64 + w*8)*64]);
      gload_lds16(Bg + (size_t)(n0 + rr)*LDAB + k0 + cs, &Bd[(q*64 + w*8)*64]);
    }
  };
  const int nt = 12;                            // K = 768, BK = 64
  STAGE(0, 0);
  STAGE(1, 1);
  asm volatile("s_waitcnt vmcnt(8)" ::: "memory");   // tile 0 landed (tile 1 in flight)
  __builtin_amdgcn_s_barrier();
  int p = 0;
  for (int kt = 0; kt < nt; ++kt) {
    const ushort* Ar = &LDS[p*16384];
    const ushort* Br = &LDS[32768 + p*16384];
    int sw0 = (lhi ^ (lrow & 7)) * 8;           // ks=0: granule lhi
    int sw1 = ((4 + lhi) ^ (lrow & 7)) * 8;     // ks=1: granule 4+lhi
    bf16x8 a0[8], b0r[4], a1[8], b1r[4];
    #pragma unroll
    for (int i = 0; i < 8; ++i)
      a0[i] = *(const bf16x8*)&Ar[(wr*128 + i*16 + lrow)*64 + sw0];
    #pragma unroll
    for (int j = 0; j < 4; ++j)
      b0r[j] = *(const bf16x8*)&Br[(wc*64 + j*16 + lrow)*64 + sw0];
    #pragma unroll
    for (int i = 0; i < 8; ++i)
      #pragma unroll
      for (int j = 0; j < 4; ++j)
        acc[i][j] = __builtin_amdgcn_mfma_f32_16x16x32_bf16(a0[i], b0r[j], acc[i][j], 0, 0, 0);
    #pragma unroll
    for (int i = 0; i < 8; ++i)
      a1[i] = *(const bf16x8*)&Ar[(wr*128 + i*16 + lrow)*64 + sw1];
    #pragma unroll
    for (int j = 0; j < 4; ++j)
      b1r[j] = *(const bf16x8*)&Br[(wc*64 + j*16 + lrow)*64 + sw1];
    asm volatile("s_waitcnt lgkmcnt(0)" ::: "memory");  // all our LDS reads complete
    __builtin_amdgcn_sched_barrier(0);
    __builtin_amdgcn_s_barrier();               // every wave done reading buf p
    if (kt + 2 < nt) STAGE(p, kt + 2);          // safe: clobbers fully-consumed buffer
    __builtin_amdgcn_s_setprio(1);
    #pragma unroll
    for (int i = 0; i < 8; ++i)
      #pragma unroll
      for (int j = 0; j < 4; ++j)
        acc[i][j] = __builtin_amdgcn_mfma_f32_16x16x32_bf16(a1[i], b1r[j], acc[i][j], 0, 0, 0);
    __builtin_amdgcn_s_setprio(0);
    if (kt + 1 < nt) {
      if (kt + 2 < nt) asm volatile("s_waitcnt vmcnt(8)" ::: "memory");  // next tile landed
      else             asm volatile("s_waitcnt vmcnt(0)" ::: "memory");
      __builtin_amdgcn_s_barrier();
    }
    p ^= 1;
  }
  // ---- epilogue ----
  if (MODE == 0 && n0 >= 1536) {
    // V tile: bias + transpose via two-pass LDS bounce -> vT[bh][d][s]
    ushort* T = LDS;                      // [128][264] per pass
    int b = m0 >> 9, s0 = m0 & 511;
    #pragma unroll
    for (int ps = 0; ps < 2; ++ps) {
      if ((wc >> 1) == ps) {
        #pragma unroll
        for (int j = 0; j < 4; ++j) {
          int dl = (wc & 1)*64 + j*16 + lrow;
          float bvv = b2[n0 - 1536 + ps*128 + dl];
          #pragma unroll
          for (int i = 0; i < 8; ++i) {
            #pragma unroll
            for (int r = 0; r < 4; ++r) {
              __hip_bfloat16 hh = __float2bfloat16(acc[i][j][r] + bvv);
              T[dl*264 + wr*128 + i*16 + lhi*4 + r] = *(ushort*)&hh;
            }
          }
        }
      }
      __syncthreads();
      #pragma unroll
      for (int it = 0; it < 8; ++it) {
        int idx = t + 512*it;
        int dl = idx >> 5, sc8 = (idx & 31)*8;
        int dg = n0 - 1536 + ps*128 + dl;
        int h = dg >> 6, dmod = dg & 63;
        bf16x8 vv = *(const bf16x8*)&T[dl*264 + sc8];
        *(bf16x8*)((ushort*)vT + ((size_t)(b*HEADS + h)*64 + dmod)*512 + s0 + sc8) = vv;
      }
      __syncthreads();
    }
    return;
  }
  #pragma unroll
  for (int i = 0; i < 8; ++i) {
    int grow = m0 + wr*128 + i*16 + lhi*4;
    #pragma unroll
    for (int j = 0; j < 4; ++j) {
      int gcol = n0 + wc*64 + j*16 + lrow;
      float bvv;
      if (MODE == 0)      bvv = (gcol < 768) ? b0[gcol] : b1[gcol-768];
      else if (MODE == 1) bvv = b0[gcol];
      else                bvv = 0.f;
      #pragma unroll
      for (int r = 0; r < 4; ++r) {
        float v = acc[i][j][r] + bvv;
        if (MODE == 1) v = fmaxf(v, 0.f);
        C[(size_t)(grow + r)*N + gcol] = __float2bfloat16(v);
      }
    }
  }
}

// ---------------- FFN2 reduce: out += bias + sum of 4 bf16 partials --------------------
__global__ __launch_bounds__(256) void ffn2_reduce_kernel(
    const __hip_bfloat16* __restrict__ p, const float* __restrict__ bias,
    float* __restrict__ out) {
  int gid = blockIdx.x*256 + threadIdx.x;
  size_t i = (size_t)gid*8;
  const ushort* pp = (const ushort*)p;
  float acc[8];
  int col = (int)(i % DM);
  #pragma unroll
  for (int j = 0; j < 8; ++j) acc[j] = bias[col + j];
  #pragma unroll
  for (int s = 0; s < 4; ++s) {
    bf16x8 v = *(const bf16x8*)(pp + (size_t)s*MROWS*DM + i);
    #pragma unroll
    for (int j = 0; j < 8; ++j) acc[j] += b2f((ushort)v[j]);
  }
  float4 o0 = *(const float4*)(out + i);
  float4 o1 = *(const float4*)(out + i + 4);
  o0.x += acc[0]; o0.y += acc[1]; o0.z += acc[2]; o0.w += acc[3];
  o1.x += acc[4]; o1.y += acc[5]; o1.z += acc[6]; o1.w += acc[7];
  *(float4*)(out + i)     = o0;
  *(float4*)(out + i + 4) = o1;
}

// ---------------- residual add + LN (wave-per-row) + gb-writer blocks ------------------
__global__ __launch_bounds__(256) void ln_res_kernel(
    const float* __restrict__ x, const __hip_bfloat16* __restrict__ a, float* __restrict__ xs,
    const float* __restrict__ g, const float* __restrict__ b, __hip_bfloat16* __restrict__ o,
    const float* __restrict__ nsWS, const float* __restrict__ cumWS,
    const float* __restrict__ prior, float* __restrict__ gp, float* __restrict__ bp) {
  int t = threadIdx.x;
  if (blockIdx.x >= 1024) {
    int row = 32768 + (blockIdx.x - 1024)*4 + (t >> 6);   // rows [32768, 49152)
    gb_rows_256(row, t, nsWS, cumWS, prior, gp, bp);
    return;
  }
  int lane = t & 63, w = t >> 6;
  int row = blockIdx.x*4 + w;
  size_t base = (size_t)row * DM;
  const ushort* ab = (const ushort*)a;
  float v[12]; float s = 0.f, s2 = 0.f;
  #pragma unroll
  for (int i = 0; i < 12; ++i) {
    int c = lane + 64*i;
    v[i] = x[base + c] + b2f(ab[base + c]);
    xs[base + c] = v[i];
    s += v[i]; s2 += v[i]*v[i];
  }
  #pragma unroll
  for (int off = 1; off < 64; off <<= 1) {
    s  += __shfl_xor(s,  off, 64);
    s2 += __shfl_xor(s2, off, 64);
  }
  float mean = s * (1.f/DM);
  float rstd = rsqrtf(s2 * (1.f/DM) - mean*mean + 1e-5f);
  #pragma unroll
  for (int i = 0; i < 12; ++i) {
    int c = lane + 64*i;
    o[base + c] = __float2bfloat16((v[i]-mean)*rstd*g[c] + b[c]);
  }
}

// ---------------- MFMA flash attention + gb-writer blocks ------------------------------
__global__ __launch_bounds__(256) void attn_mfma_kernel(
    const __hip_bfloat16* __restrict__ qk, const __hip_bfloat16* __restrict__ vT,
    const float* __restrict__ cumWS, const float* __restrict__ prior,
    __hip_bfloat16* __restrict__ att,
    const float* __restrict__ nsWS, float* __restrict__ gp, float* __restrict__ bp) {
  __shared__ ushort Ps[4][16][72];
  int t = threadIdx.x;
  int bidx = blockIdx.x;
  if (bidx >= 768) {
    int row = (bidx - 768)*4 + (t >> 6);   // rows [0, 32768)
    gb_rows_256(row, t, nsWS, cumWS, prior, gp, bp);
    return;
  }
  int lane = t & 63, wid = t >> 6;
  int tile = (bidx & 7)*96 + (bidx >> 3);
  int qt = tile & 7, bh = tile >> 3;
  int b = bh / HEADS, h = bh % HEADS;
  int lrow = lane & 15, lhi = lane >> 4;
  int qbase = qt*64 + wid*16;
  const ushort* qg = (const ushort*)qk;
  bf16x8 aq[2];
  {
    const ushort* qp = qg + (size_t)(b*SEQ + qbase + lrow)*2304 + h*64 + lhi*8;
    aq[0] = *(const bf16x8*)qp;
    aq[1] = *(const bf16x8*)(qp + 32);
  }
  const float* cum = cumWS + (size_t)bh*SEQ;
  float pr = prior[0];
  float c0 = pr + (1.f - pr)*0.01f;
  int qrow[4]; float cq[4];
  #pragma unroll
  for (int r = 0; r < 4; ++r) { qrow[r] = qbase + lhi*4 + r; cq[r] = cum[qrow[r]]; }
  float lsum[4] = {0.f, 0.f, 0.f, 0.f};
  f32x4 oacc[4] = {};
  const ushort* kg = qg + 768;
  const ushort* vg = (const ushort*)vT;
  for (int kt = 0; kt < 8; ++kt) {
    f32x4 sacc[4] = {};
    #pragma unroll
    for (int j = 0; j < 4; ++j) {
      const ushort* kp = kg + (size_t)(b*SEQ + kt*64 + j*16 + lrow)*2304 + h*64 + lhi*8;
      bf16x8 bk0 = *(const bf16x8*)kp;
      bf16x8 bk1 = *(const bf16x8*)(kp + 32);
      sacc[j] = __builtin_amdgcn_mfma_f32_16x16x32_bf16(aq[0], bk0, sacc[j], 0, 0, 0);
      sacc[j] = __builtin_amdgcn_mfma_f32_16x16x32_bf16(aq[1], bk1, sacc[j], 0, 0, 0);
    }
    float ck[4];
    #pragma unroll
    for (int j = 0; j < 4; ++j) ck[j] = cum[kt*64 + j*16 + lrow];
    #pragma unroll
    for (int j = 0; j < 4; ++j) {
      int kk = kt*64 + j*16 + lrow;
      #pragma unroll
      for (int r = 0; r < 4; ++r) {
        float e = __expf(fminf(sacc[j][r]*0.125f - 16.f, 60.f));
        lsum[r] += e;
        float dd = ck[j] - cq[r];
        float gpv = (kk == qrow[r]) ? c0 : (__expf((kk > qrow[r]) ? dd : -dd) + 1e-4f);
        __hip_bfloat16 pb = __float2bfloat16(e * gpv);
        Ps[wid][lhi*4 + r][j*16 + lrow] = *(ushort*)&pb;
      }
    }
    asm volatile("s_waitcnt lgkmcnt(0)" ::: "memory");
    __builtin_amdgcn_s_setprio(1);
    #pragma unroll
    for (int c = 0; c < 2; ++c) {
      bf16x8 ap = *(const bf16x8*)&Ps[wid][lrow][c*32 + lhi*8];
      #pragma unroll
      for (int dj = 0; dj < 4; ++dj) {
        const ushort* vp = vg + ((size_t)bh*64 + dj*16 + lrow)*512 + kt*64 + c*32 + lhi*8;
        bf16x8 bv = *(const bf16x8*)vp;
        oacc[dj] = __builtin_amdgcn_mfma_f32_16x16x32_bf16(ap, bv, oacc[dj], 0, 0, 0);
      }
    }
    __builtin_amdgcn_s_setprio(0);
  }
  #pragma unroll
  for (int off = 1; off < 16; off <<= 1) {
    #pragma unroll
    for (int r = 0; r < 4; ++r) lsum[r] += __shfl_xor(lsum[r], off, 64);
  }
  float inv[4];
  #pragma unroll
  for (int r = 0; r < 4; ++r) inv[r] = 1.f / lsum[r];
  #pragma unroll
  for (int dj = 0; dj < 4; ++dj) {
    #pragma unroll
    for (int r = 0; r < 4; ++r) {
      float v = oacc[dj][r] * inv[r];
      att[(size_t)(b*SEQ + qbase + lhi*4 + r)*DM + h*64 + dj*16 + lrow] = __float2bfloat16(v);
    }
  }
}

// ======================================================================================
extern "C" void kernel_launch(void* const* d_in, const int* in_sizes, int n_in,
                              void* d_out, int out_size, void* d_ws, size_t ws_size,
                              hipStream_t stream) {
  const float* x      = (const float*)d_in[0];
  const float* prior  = (const float*)d_in[2];
  const float* ga_g   = (const float*)d_in[3];
  const float* ga_b   = (const float*)d_in[4];
  const float* ga_wq  = (const float*)d_in[5];
  const float* ga_bq  = (const float*)d_in[6];
  const float* ga_wk  = (const float*)d_in[7];
  const float* ga_bk  = (const float*)d_in[8];
  const float* sa_wq  = (const float*)d_in[9];
  const float* sa_bq  = (const float*)d_in[10];
  const float* sa_wk  = (const float*)d_in[11];
  const float* sa_bk  = (const float*)d_in[12];
  const float* sa_wv  = (const float*)d_in[13];
  const float* sa_bv  = (const float*)d_in[14];
  const float* ff_w1  = (const float*)d_in[15];
  const float* ff_b1  = (const float*)d_in[16];
  const float* ff_w2  = (const float*)d_in[17];
  const float* ff_b2  = (const float*)d_in[18];
  const float* sl0_g  = (const float*)d_in[19];
  const float* sl0_b  = (const float*)d_in[20];
  const float* sl1_g  = (const float*)d_in[21];
  const float* sl1_b  = (const float*)d_in[22];

  float* out_x  = (float*)d_out;
  float* out_gp = out_x  + (size_t)MROWS*DM;
  float* out_bp = out_gp + (size_t)BH*SEQ*SEQ;

  char* W = (char*)d_ws;
  __hip_bfloat16* ln0    = (__hip_bfloat16*)(W + 0);          // 6.29 MB
  __hip_bfloat16* lnga   = (__hip_bfloat16*)(W + 6291456);    // 6.29 MB
  float* Qg   = (float*)(W + 12582912);                       // 12.58 MB
  float* Kg   = (float*)(W + 25165824);                       // 12.58 MB
  __hip_bfloat16* qkv3   = (__hip_bfloat16*)(W + 37748736);   // 18.87 MB [4096][2304]
  __hip_bfloat16* vT     = (__hip_bfloat16*)(W + 56623104);   // 6.29 MB
  __hip_bfloat16* attbuf = (__hip_bfloat16*)(W + 62914560);   // 6.29 MB
  __hip_bfloat16* ln1    = (__hip_bfloat16*)(W + 69206016);   // 6.29 MB
  __hip_bfloat16* wqkv   = (__hip_bfloat16*)(W + 75497472);   // 3.54 MB
  __hip_bfloat16* w1     = (__hip_bfloat16*)(W + 79036416);   // 4.72 MB
  __hip_bfloat16* w2     = (__hip_bfloat16*)(W + 83755008);   // 4.72 MB
  __hip_bfloat16* hbuf   = (__hip_bfloat16*)(W + 88473600);   // 25.17 MB [4096][3072]
  __hip_bfloat16* parts  = (__hip_bfloat16*)(W + 113639424);  // 25.17 MB (4 x 6.29)
  float* nsWS  = (float*)(W + 138805248);
  float* cumWS = (float*)(W + 139001856);

  // 1. dual pre-norm (both bf16) + weight conversions
  ln_cvt_kernel<<<7360, 256, 0, stream>>>(
      x, sl0_g, sl0_b, ln0, ga_g, ga_b, lnga,
      sa_wq, sa_wk, sa_wv, ff_w1, ff_w2, wqkv, w1, w2);
  // 2. QKV GEMM (V transposed in-epilogue) || GA q/k projection (role-split)
  gemm256_kernel<0><<<240, 512, 0, stream>>>(
      ln0, wqkv, sa_bq, sa_bk, sa_bv, qkv3, vT,
      lnga, ga_wq, ga_bq, ga_wk, ga_bk, Qg, Kg);
  // 3. tridiagonal softmax -> ns + cum
  ga_edges_kernel<<<BH, SEQ, 0, stream>>>(Qg, Kg, prior, nsWS, cumWS);
  // 4. flash attention + writer rows [0,32768)
  attn_mfma_kernel<<<768 + 8192, 256, 0, stream>>>(
      qkv3, vT, cumWS, prior, attbuf, nsWS, out_gp, out_bp);
  // 5. residual + pre-norm for FFN + writer rows [32768,49152)
  ln_res_kernel<<<1024 + 4096, 256, 0, stream>>>(
      x, attbuf, out_x, sl1_g, sl1_b, ln1,
      nsWS, cumWS, prior, out_gp, out_bp);
  // 6. FFN1 GEMM (pure)
  gemm256_kernel<1><<<192, 512, 0, stream>>>(
      ln1, w1, ff_b1, nullptr, nullptr, hbuf, nullptr,
      nullptr, nullptr, nullptr, nullptr, nullptr, nullptr, nullptr);
  // 7. FFN2 split-K x4 (bf16 partials)
  gemm256_kernel<2><<<192, 512, 0, stream>>>(
      hbuf, w2, nullptr, nullptr, nullptr, parts, nullptr,
      nullptr, nullptr, nullptr, nullptr, nullptr, nullptr, nullptr);
  // 8. reduce partials + bias + residual
  ffn2_reduce_kernel<<<1536, 256, 0, stream>>>(parts, ff_b2, out_x);
}

// Round 11
// 233.227 us; speedup vs baseline: 1.4217x; 1.0442x over previous
//
#include <hip/hip_runtime.h>
#include <hip/hip_bf16.h>

#define HEADS 12
#define DM    768
#define DKH   64
#define DFF   3072
#define BSZ   8
#define SEQ   512
#define MROWS (BSZ*SEQ)   // 4096
#define BH    (BSZ*HEADS) // 96

typedef __attribute__((ext_vector_type(8))) short bf16x8;
typedef __attribute__((ext_vector_type(4))) float f32x4;

__device__ __forceinline__ void gload_lds16(const ushort* g, ushort* l) {
  __builtin_amdgcn_global_load_lds(
      (const __attribute__((address_space(1))) unsigned int*)g,
      (__attribute__((address_space(3))) unsigned int*)l, 16, 0, 0);
}

__device__ __forceinline__ float b2f(ushort u) {
  union { unsigned int i; float f; } c; c.i = (unsigned int)u << 16; return c.f;
}

// ---------------- gb-writer device fns (group/break prob rows) -------------------------
// 512-thr: 4 rows/block, 128 thr/row, 4 cols/thread
__device__ __forceinline__ void gb_rows_512(
    int row, int t, const float* __restrict__ nsWS, const float* __restrict__ cumWS,
    const float* __restrict__ prior, float* __restrict__ gp, float* __restrict__ bp) {
  int bh = row >> 9, q = row & 511;
  const float* cum = cumWS + (size_t)bh*SEQ;
  const float* ns  = nsWS  + (size_t)bh*SEQ;
  float pr = prior[0];
  float c0 = pr + (1.f - pr)*0.01f;
  float cq = cum[q];
  size_t rb = ((size_t)bh*SEQ + q)*SEQ;
  int k0 = (t & 127)*4;
  float4 g4, b4;
  float* gv = (float*)&g4; float* bv = (float*)&b4;
  #pragma unroll
  for (int j = 0; j < 4; ++j) {
    int k = k0 + j;
    float g;
    if (k == q) g = c0;
    else {
      float c = cum[k];
      g = __expf((k > q) ? (c - cq) : (cq - c)) + 1e-4f;
    }
    float bb = c0;
    if (k == q+1)      bb = ns[q];
    else if (k+1 == q) bb = ns[q-1];
    gv[j] = g; bv[j] = bb;
  }
  *(float4*)(gp + rb + k0) = g4;
  *(float4*)(bp + rb + k0) = b4;
}

// 256-thr: 4 rows/block, 64 thr/row, 8 cols/thread
__device__ __forceinline__ void gb_rows_256(
    int row, int t, const float* __restrict__ nsWS, const float* __restrict__ cumWS,
    const float* __restrict__ prior, float* __restrict__ gp, float* __restrict__ bp) {
  int bh = row >> 9, q = row & 511;
  const float* cum = cumWS + (size_t)bh*SEQ;
  const float* ns  = nsWS  + (size_t)bh*SEQ;
  float pr = prior[0];
  float c0 = pr + (1.f - pr)*0.01f;
  float cq = cum[q];
  size_t rb = ((size_t)bh*SEQ + q)*SEQ;
  int k0 = (t & 63)*8;
  float g8[8], b8[8];
  #pragma unroll
  for (int j = 0; j < 8; ++j) {
    int k = k0 + j;
    float g;
    if (k == q) g = c0;
    else {
      float c = cum[k];
      g = __expf((k > q) ? (c - cq) : (cq - c)) + 1e-4f;
    }
    float bb = c0;
    if (k == q+1)      bb = ns[q];
    else if (k+1 == q) bb = ns[q-1];
    g8[j] = g; b8[j] = bb;
  }
  *(float4*)(gp + rb + k0)     = *(float4*)&g8[0];
  *(float4*)(gp + rb + k0 + 4) = *(float4*)&g8[4];
  *(float4*)(bp + rb + k0)     = *(float4*)&b8[0];
  *(float4*)(bp + rb + k0 + 4) = *(float4*)&b8[4];
}

// ---------------- fused: dual pre-norm (both outputs bf16) + weight cvt ----------------
__global__ __launch_bounds__(256) void ln_cvt_kernel(
    const float* __restrict__ x,
    const float* __restrict__ g0, const float* __restrict__ b0, __hip_bfloat16* __restrict__ ln0,
    const float* __restrict__ gg, const float* __restrict__ gb, __hip_bfloat16* __restrict__ lnga,
    const float* __restrict__ swq, const float* __restrict__ swk, const float* __restrict__ swv,
    const float* __restrict__ w1s, const float* __restrict__ w2s,
    __hip_bfloat16* __restrict__ dqkv, __hip_bfloat16* __restrict__ d1,
    __hip_bfloat16* __restrict__ d2) {
  int t = threadIdx.x;
  if (blockIdx.x >= 1024) {
    long gid = (long)(blockIdx.x - 1024)*256 + t;
    long i = gid*4;
    const float* s; __hip_bfloat16* d; long off;
    if (i < 1769472L) {
      long j = i / 589824L; off = i - j*589824L;
      s = (j == 0) ? swq : (j == 1) ? swk : swv;
      d = dqkv + j*589824L;
    } else if (i < 4128768L) {
      off = i - 1769472L; s = w1s; d = d1;
    } else {
      off = i - 4128768L; s = w2s; d = d2;
    }
    float4 v = *(const float4*)(s + off);
    d[off+0] = __float2bfloat16(v.x);
    d[off+1] = __float2bfloat16(v.y);
    d[off+2] = __float2bfloat16(v.z);
    d[off+3] = __float2bfloat16(v.w);
    return;
  }
  int lane = t & 63, w = t >> 6;
  int row = blockIdx.x*4 + w;
  size_t base = (size_t)row * DM;
  float v[12]; float s = 0.f, s2 = 0.f;
  #pragma unroll
  for (int i = 0; i < 12; ++i) {
    v[i] = x[base + lane + 64*i];
    s += v[i]; s2 += v[i]*v[i];
  }
  #pragma unroll
  for (int off = 1; off < 64; off <<= 1) {
    s  += __shfl_xor(s,  off, 64);
    s2 += __shfl_xor(s2, off, 64);
  }
  float mean = s * (1.f/DM);
  float rstd = rsqrtf(s2 * (1.f/DM) - mean*mean + 1e-5f);
  #pragma unroll
  for (int i = 0; i < 12; ++i) {
    int c = lane + 64*i;
    float h = (v[i]-mean)*rstd;
    ln0[base + c]  = __float2bfloat16(h*g0[c] + b0[c]);
    lnga[base + c] = __float2bfloat16(h*gg[c] + gb[c]);
  }
}

// ---------------- tridiagonal softmax -> ns + prefix log-cumsum (wave scan) ------------
__global__ __launch_bounds__(512) void ga_edges_kernel(
    const float* __restrict__ Qg, const float* __restrict__ Kg,
    const float* __restrict__ prior, float* __restrict__ nsWS, float* __restrict__ cumWS) {
  __shared__ float pu[SEQ], pd[SEQ];
  __shared__ float wsum[8], wpre[8];
  int bh = blockIdx.x, m = threadIdx.x;
  const float* Qb = Qg + (size_t)bh*SEQ*DKH;
  const float* Kb = Kg + (size_t)bh*SEQ*DKH;
  const float4* qm = (const float4*)(Qb + (size_t)m*DKH);
  float su = -1e4f, sd = -1e4f;
  if (m < SEQ-1) {
    const float4* kn = (const float4*)(Kb + (size_t)(m+1)*DKH);
    float a = 0.f;
    #pragma unroll
    for (int i = 0; i < 16; ++i) {
      float4 q4 = qm[i], k4 = kn[i];
      a += q4.x*k4.x + q4.y*k4.y + q4.z*k4.z + q4.w*k4.w;
    }
    su = a * (1.f/DKH);
  }
  if (m >= 1) {
    const float4* kp = (const float4*)(Kb + (size_t)(m-1)*DKH);
    float a = 0.f;
    #pragma unroll
    for (int i = 0; i < 16; ++i) {
      float4 q4 = qm[i], k4 = kp[i];
      a += q4.x*k4.x + q4.y*k4.y + q4.z*k4.z + q4.w*k4.w;
    }
    sd = a * (1.f/DKH);
  }
  float mx = fmaxf(su, sd);
  float eu = __expf(su - mx), ed = __expf(sd - mx);
  float inv = 1.f / (eu + ed);
  pu[m] = eu * inv;
  pd[m] = ed * inv;
  __syncthreads();
  float pr = prior[0];
  float nsv = 0.f, lg = 0.f;
  if (m < SEQ-1) {
    float vv = sqrtf(pu[m]*pd[m+1] + 1e-4f);
    nsv = pr + (1.f - pr)*vv;
    lg = __logf(nsv + 1e-9f);
  }
  float v = lg;
  #pragma unroll
  for (int off = 1; off < 64; off <<= 1) {
    float u = __shfl_up(v, off, 64);
    if ((m & 63) >= off) v += u;
  }
  if ((m & 63) == 63) wsum[m >> 6] = v;
  __syncthreads();
  if (m == 0) {
    float a = 0.f;
    #pragma unroll
    for (int i = 0; i < 8; ++i) { wpre[i] = a; a += wsum[i]; }
  }
  __syncthreads();
  float incl = v + wpre[m >> 6];
  nsWS[(size_t)bh*SEQ + m] = nsv;
  cumWS[(size_t)bh*SEQ + m] = incl - lg;   // exclusive scan
}

// ---------------- 256x256 8-wave counted-vmcnt MFMA GEMM + fused roles -----------------
// MODE 0: QKV: q/k cols -> qkv3; V cols -> transposed into vT. Blocks [144,240): GA proj.
// MODE 1: FFN1 (bias+relu) + gb-writer rows [16384,32768)
// MODE 2: FFN2 split-K x4 (192 GEMM blocks) + gb-writer rows [32768,49152)
template<int MODE>
__global__ __launch_bounds__(512, 2) void gemm256_kernel(
    const __hip_bfloat16* __restrict__ A, const __hip_bfloat16* __restrict__ B,
    const float* __restrict__ b0, const float* __restrict__ b1, const float* __restrict__ b2,
    __hip_bfloat16* __restrict__ C, __hip_bfloat16* __restrict__ vT,
    const float* __restrict__ nsWS, const float* __restrict__ cumWS,
    const float* __restrict__ prior, float* __restrict__ gp, float* __restrict__ bp,
    const __hip_bfloat16* __restrict__ lnga,
    const float* __restrict__ gwq, const float* __restrict__ gbq,
    const float* __restrict__ gwk, const float* __restrict__ gbk,
    float* __restrict__ Qg, float* __restrict__ Kg) {
  constexpr int N    = (MODE==0) ? 2304 : (MODE==1) ? 3072 : 768;
  constexpr int TN   = N / 256;
  constexpr int LDAB = (MODE==2) ? 3072 : 768;
  constexpr int NT   = (MODE==0) ? 144 : 192;
  __shared__ ushort LDS[65536];          // 128 KB
  int t = threadIdx.x;
  int bidx = blockIdx.x;
  if (bidx >= NT) {
    if (MODE == 0) {
      // ---- GA q/k projection: 2 tasks (h, 256-row chunk) per block ----
      ushort* WQ = LDS;                  // [64][72]
      ushort* WK = LDS + 4608;
      for (int i = t; i < 4096; i += 512) {
        int d = i >> 6, c = i & 63;
        __hip_bfloat16 q = __float2bfloat16(gwq[i]);
        __hip_bfloat16 k = __float2bfloat16(gwk[i]);
        WQ[d*72 + c] = *(ushort*)&q;
        WK[d*72 + c] = *(ushort*)&k;
      }
      __syncthreads();
      int task = (bidx - 144)*2 + (t >> 8);
      int h  = task >> 4;
      int r0 = (task & 15) * 256;
      int t2 = t & 255;
      int lane = t2 & 63, w = t2 >> 6;
      int lrow = lane & 15, lhi = lane >> 4;
      const ushort* Ag2 = (const ushort*)lnga;
      bf16x8 a[4][2];
      #pragma unroll
      for (int i = 0; i < 4; ++i)
        #pragma unroll
        for (int ks = 0; ks < 2; ++ks)
          a[i][ks] = *(const bf16x8*)(Ag2 + (size_t)(r0 + w*64 + i*16 + lrow)*DM + h*64 + ks*32 + lhi*8);
      int b = r0 >> 9;
      #pragma unroll
      for (int qk = 0; qk < 2; ++qk) {
        const ushort* Wm = qk ? WK : WQ;
        const float* bias = qk ? gbk : gbq;
        float* Og = qk ? Kg : Qg;
        bf16x8 bf[4][2];
        #pragma unroll
        for (int j = 0; j < 4; ++j)
          #pragma unroll
          for (int ks = 0; ks < 2; ++ks)
            bf[j][ks] = *(const bf16x8*)&Wm[(j*16 + lrow)*72 + ks*32 + lhi*8];
        f32x4 acc[4][4] = {};
        #pragma unroll
        for (int i = 0; i < 4; ++i)
          #pragma unroll
          for (int j = 0; j < 4; ++j) {
            acc[i][j] = __builtin_amdgcn_mfma_f32_16x16x32_bf16(a[i][0], bf[j][0], acc[i][j], 0, 0, 0);
            acc[i][j] = __builtin_amdgcn_mfma_f32_16x16x32_bf16(a[i][1], bf[j][1], acc[i][j], 0, 0, 0);
          }
        #pragma unroll
        for (int i = 0; i < 4; ++i) {
          int rowb = r0 + w*64 + i*16 + lhi*4;
          #pragma unroll
          for (int j = 0; j < 4; ++j) {
            int d = j*16 + lrow;
            float bv = bias[d];
            #pragma unroll
            for (int r = 0; r < 4; ++r) {
              int sIdx = (rowb + r) & 511;
              Og[(((size_t)b*HEADS + h)*SEQ + sIdx)*DKH + d] = acc[i][j][r] + bv;
            }
          }
        }
      }
    } else {
      // ---- gb writer: 4 q-rows per block (hides on the ~64 CUs the GEMM leaves idle) --
      int base = (MODE == 1) ? 16384 : 32768;
      int row = base + (bidx - NT)*4 + (t >> 7);
      gb_rows_512(row, t, nsWS, cumWS, prior, gp, bp);
    }
    return;
  }
  int lane = t & 63, w = t >> 6;
  int rin = lane >> 3, gr = lane & 7;
  int lrow = lane & 15, lhi = lane >> 4;
  int z = 0, tl = bidx;
  if (MODE == 2) { z = bidx / 48; tl = bidx % 48; }
  constexpr int NTIL = (MODE==2) ? 48 : NT;
  int tile = (tl & 7)*(NTIL/8) + (tl >> 3);     // XCD swizzle (NTIL % 8 == 0)
  int m0 = (tile / TN) * 256;
  int n0 = (tile % TN) * 256;
  int kOff = (MODE == 2) ? z * 768 : 0;
  if (MODE == 2) C += (size_t)z * MROWS * 768;
  int wr = w >> 2, wc = w & 3;
  const ushort* Ag = (const ushort*)A;
  const ushort* Bg = (const ushort*)B;
  f32x4 acc[8][4] = {};
  // LDS content swizzle via pre-swizzled GLOBAL source (dest stays linear).
  auto STAGE = [&](int p, int kt) {
    int k0 = kOff + kt*64;
    ushort* Ad = &LDS[p*16384];
    ushort* Bd = &LDS[32768 + p*16384];
    int cs = (gr ^ rin) * 8;
    #pragma unroll
    for (int q = 0; q < 4; ++q) {
      int rr = q*64 + w*8 + rin;               // rr & 7 == rin
      gload_lds16(Ag + (size_t)(m0 + rr)*LDAB + k0 + cs, &Ad[(q*64 + w*8)*64]);
      gload_lds16(Bg + (size_t)(n0 + rr)*LDAB + k0 + cs, &Bd[(q*64 + w*8)*64]);
    }
  };
  const int nt = 12;                            // K = 768, BK = 64
  STAGE(0, 0);
  STAGE(1, 1);
  asm volatile("s_waitcnt vmcnt(8)" ::: "memory");   // tile 0 landed (tile 1 in flight)
  __builtin_amdgcn_s_barrier();
  int p = 0;
  for (int kt = 0; kt < nt; ++kt) {
    const ushort* Ar = &LDS[p*16384];
    const ushort* Br = &LDS[32768 + p*16384];
    int sw0 = (lhi ^ (lrow & 7)) * 8;           // ks=0: granule lhi
    int sw1 = ((4 + lhi) ^ (lrow & 7)) * 8;     // ks=1: granule 4+lhi
    bf16x8 a0[8], b0r[4], a1[8], b1r[4];
    #pragma unroll
    for (int i = 0; i < 8; ++i)
      a0[i] = *(const bf16x8*)&Ar[(wr*128 + i*16 + lrow)*64 + sw0];
    #pragma unroll
    for (int j = 0; j < 4; ++j)
      b0r[j] = *(const bf16x8*)&Br[(wc*64 + j*16 + lrow)*64 + sw0];
    #pragma unroll
    for (int i = 0; i < 8; ++i)
      #pragma unroll
      for (int j = 0; j < 4; ++j)
        acc[i][j] = __builtin_amdgcn_mfma_f32_16x16x32_bf16(a0[i], b0r[j], acc[i][j], 0, 0, 0);
    #pragma unroll
    for (int i = 0; i < 8; ++i)
      a1[i] = *(const bf16x8*)&Ar[(wr*128 + i*16 + lrow)*64 + sw1];
    #pragma unroll
    for (int j = 0; j < 4; ++j)
      b1r[j] = *(const bf16x8*)&Br[(wc*64 + j*16 + lrow)*64 + sw1];
    asm volatile("s_waitcnt lgkmcnt(0)" ::: "memory");  // all our LDS reads complete
    __builtin_amdgcn_sched_barrier(0);
    __builtin_amdgcn_s_barrier();               // every wave done reading buf p
    if (kt + 2 < nt) STAGE(p, kt + 2);          // safe: clobbers fully-consumed buffer
    __builtin_amdgcn_s_setprio(1);
    #pragma unroll
    for (int i = 0; i < 8; ++i)
      #pragma unroll
      for (int j = 0; j < 4; ++j)
        acc[i][j] = __builtin_amdgcn_mfma_f32_16x16x32_bf16(a1[i], b1r[j], acc[i][j], 0, 0, 0);
    __builtin_amdgcn_s_setprio(0);
    if (kt + 1 < nt) {
      if (kt + 2 < nt) asm volatile("s_waitcnt vmcnt(8)" ::: "memory");  // next tile landed
      else             asm volatile("s_waitcnt vmcnt(0)" ::: "memory");
      __builtin_amdgcn_s_barrier();
    }
    p ^= 1;
  }
  // ---- epilogue ----
  if (MODE == 0 && n0 >= 1536) {
    // V tile: bias + transpose via two-pass LDS bounce -> vT[bh][d][s]
    ushort* T = LDS;                      // [128][264] per pass
    int b = m0 >> 9, s0 = m0 & 511;
    #pragma unroll
    for (int ps = 0; ps < 2; ++ps) {
      if ((wc >> 1) == ps) {
        #pragma unroll
        for (int j = 0; j < 4; ++j) {
          int dl = (wc & 1)*64 + j*16 + lrow;
          float bvv = b2[n0 - 1536 + ps*128 + dl];
          #pragma unroll
          for (int i = 0; i < 8; ++i) {
            #pragma unroll
            for (int r = 0; r < 4; ++r) {
              __hip_bfloat16 hh = __float2bfloat16(acc[i][j][r] + bvv);
              T[dl*264 + wr*128 + i*16 + lhi*4 + r] = *(ushort*)&hh;
            }
          }
        }
      }
      __syncthreads();
      #pragma unroll
      for (int it = 0; it < 8; ++it) {
        int idx = t + 512*it;
        int dl = idx >> 5, sc8 = (idx & 31)*8;
        int dg = n0 - 1536 + ps*128 + dl;
        int h = dg >> 6, dmod = dg & 63;
        bf16x8 vv = *(const bf16x8*)&T[dl*264 + sc8];
        *(bf16x8*)((ushort*)vT + ((size_t)(b*HEADS + h)*64 + dmod)*512 + s0 + sc8) = vv;
      }
      __syncthreads();
    }
    return;
  }
  #pragma unroll
  for (int i = 0; i < 8; ++i) {
    int grow = m0 + wr*128 + i*16 + lhi*4;
    #pragma unroll
    for (int j = 0; j < 4; ++j) {
      int gcol = n0 + wc*64 + j*16 + lrow;
      float bvv;
      if (MODE == 0)      bvv = (gcol < 768) ? b0[gcol] : b1[gcol-768];
      else if (MODE == 1) bvv = b0[gcol];
      else                bvv = 0.f;
      #pragma unroll
      for (int r = 0; r < 4; ++r) {
        float v = acc[i][j][r] + bvv;
        if (MODE == 1) v = fmaxf(v, 0.f);
        C[(size_t)(grow + r)*N + gcol] = __float2bfloat16(v);
      }
    }
  }
}

// ---------------- FFN2 reduce: out += bias + sum of 4 bf16 partials --------------------
__global__ __launch_bounds__(256) void ffn2_reduce_kernel(
    const __hip_bfloat16* __restrict__ p, const float* __restrict__ bias,
    float* __restrict__ out) {
  int gid = blockIdx.x*256 + threadIdx.x;
  size_t i = (size_t)gid*8;
  const ushort* pp = (const ushort*)p;
  float acc[8];
  int col = (int)(i % DM);
  #pragma unroll
  for (int j = 0; j < 8; ++j) acc[j] = bias[col + j];
  #pragma unroll
  for (int s = 0; s < 4; ++s) {
    bf16x8 v = *(const bf16x8*)(pp + (size_t)s*MROWS*DM + i);
    #pragma unroll
    for (int j = 0; j < 8; ++j) acc[j] += b2f((ushort)v[j]);
  }
  float4 o0 = *(const float4*)(out + i);
  float4 o1 = *(const float4*)(out + i + 4);
  o0.x += acc[0]; o0.y += acc[1]; o0.z += acc[2]; o0.w += acc[3];
  o1.x += acc[4]; o1.y += acc[5]; o1.z += acc[6]; o1.w += acc[7];
  *(float4*)(out + i)     = o0;
  *(float4*)(out + i + 4) = o1;
}

// ---------------- residual add + LN (wave-per-row) -------------------------------------
__global__ __launch_bounds__(256) void ln_res_kernel(
    const float* __restrict__ x, const __hip_bfloat16* __restrict__ a, float* __restrict__ xs,
    const float* __restrict__ g, const float* __restrict__ b, __hip_bfloat16* __restrict__ o) {
  int t = threadIdx.x;
  int lane = t & 63, w = t >> 6;
  int row = blockIdx.x*4 + w;
  size_t base = (size_t)row * DM;
  const ushort* ab = (const ushort*)a;
  float v[12]; float s = 0.f, s2 = 0.f;
  #pragma unroll
  for (int i = 0; i < 12; ++i) {
    int c = lane + 64*i;
    v[i] = x[base + c] + b2f(ab[base + c]);
    xs[base + c] = v[i];
    s += v[i]; s2 += v[i]*v[i];
  }
  #pragma unroll
  for (int off = 1; off < 64; off <<= 1) {
    s  += __shfl_xor(s,  off, 64);
    s2 += __shfl_xor(s2, off, 64);
  }
  float mean = s * (1.f/DM);
  float rstd = rsqrtf(s2 * (1.f/DM) - mean*mean + 1e-5f);
  #pragma unroll
  for (int i = 0; i < 12; ++i) {
    int c = lane + 64*i;
    o[base + c] = __float2bfloat16((v[i]-mean)*rstd*g[c] + b[c]);
  }
}

// ---------------- MFMA flash attention + gb-writer blocks ------------------------------
__global__ __launch_bounds__(256) void attn_mfma_kernel(
    const __hip_bfloat16* __restrict__ qk, const __hip_bfloat16* __restrict__ vT,
    const float* __restrict__ cumWS, const float* __restrict__ prior,
    __hip_bfloat16* __restrict__ att,
    const float* __restrict__ nsWS, float* __restrict__ gp, float* __restrict__ bp) {
  __shared__ ushort Ps[4][16][72];
  int t = threadIdx.x;
  int bidx = blockIdx.x;
  if (bidx >= 768) {
    int row = (bidx - 768)*4 + (t >> 6);   // rows [0, 16384)
    gb_rows_256(row, t, nsWS, cumWS, prior, gp, bp);
    return;
  }
  int lane = t & 63, wid = t >> 6;
  int tile = (bidx & 7)*96 + (bidx >> 3);
  int qt = tile & 7, bh = tile >> 3;
  int b = bh / HEADS, h = bh % HEADS;
  int lrow = lane & 15, lhi = lane >> 4;
  int qbase = qt*64 + wid*16;
  const ushort* qg = (const ushort*)qk;
  bf16x8 aq[2];
  {
    const ushort* qp = qg + (size_t)(b*SEQ + qbase + lrow)*2304 + h*64 + lhi*8;
    aq[0] = *(const bf16x8*)qp;
    aq[1] = *(const bf16x8*)(qp + 32);
  }
  const float* cum = cumWS + (size_t)bh*SEQ;
  float pr = prior[0];
  float c0 = pr + (1.f - pr)*0.01f;
  int qrow[4]; float cq[4];
  #pragma unroll
  for (int r = 0; r < 4; ++r) { qrow[r] = qbase + lhi*4 + r; cq[r] = cum[qrow[r]]; }
  float lsum[4] = {0.f, 0.f, 0.f, 0.f};
  f32x4 oacc[4] = {};
  const ushort* kg = qg + 768;
  const ushort* vg = (const ushort*)vT;
  for (int kt = 0; kt < 8; ++kt) {
    f32x4 sacc[4] = {};
    #pragma unroll
    for (int j = 0; j < 4; ++j) {
      const ushort* kp = kg + (size_t)(b*SEQ + kt*64 + j*16 + lrow)*2304 + h*64 + lhi*8;
      bf16x8 bk0 = *(const bf16x8*)kp;
      bf16x8 bk1 = *(const bf16x8*)(kp + 32);
      sacc[j] = __builtin_amdgcn_mfma_f32_16x16x32_bf16(aq[0], bk0, sacc[j], 0, 0, 0);
      sacc[j] = __builtin_amdgcn_mfma_f32_16x16x32_bf16(aq[1], bk1, sacc[j], 0, 0, 0);
    }
    float ck[4];
    #pragma unroll
    for (int j = 0; j < 4; ++j) ck[j] = cum[kt*64 + j*16 + lrow];
    #pragma unroll
    for (int j = 0; j < 4; ++j) {
      int kk = kt*64 + j*16 + lrow;
      #pragma unroll
      for (int r = 0; r < 4; ++r) {
        float e = __expf(fminf(sacc[j][r]*0.125f - 16.f, 60.f));
        lsum[r] += e;
        float dd = ck[j] - cq[r];
        float gpv = (kk == qrow[r]) ? c0 : (__expf((kk > qrow[r]) ? dd : -dd) + 1e-4f);
        __hip_bfloat16 pb = __float2bfloat16(e * gpv);
        Ps[wid][lhi*4 + r][j*16 + lrow] = *(ushort*)&pb;
      }
    }
    asm volatile("s_waitcnt lgkmcnt(0)" ::: "memory");
    __builtin_amdgcn_s_setprio(1);
    #pragma unroll
    for (int c = 0; c < 2; ++c) {
      bf16x8 ap = *(const bf16x8*)&Ps[wid][lrow][c*32 + lhi*8];
      #pragma unroll
      for (int dj = 0; dj < 4; ++dj) {
        const ushort* vp = vg + ((size_t)bh*64 + dj*16 + lrow)*512 + kt*64 + c*32 + lhi*8;
        bf16x8 bv = *(const bf16x8*)vp;
        oacc[dj] = __builtin_amdgcn_mfma_f32_16x16x32_bf16(ap, bv, oacc[dj], 0, 0, 0);
      }
    }
    __builtin_amdgcn_s_setprio(0);
  }
  #pragma unroll
  for (int off = 1; off < 16; off <<= 1) {
    #pragma unroll
    for (int r = 0; r < 4; ++r) lsum[r] += __shfl_xor(lsum[r], off, 64);
  }
  float inv[4];
  #pragma unroll
  for (int r = 0; r < 4; ++r) inv[r] = 1.f / lsum[r];
  #pragma unroll
  for (int dj = 0; dj < 4; ++dj) {
    #pragma unroll
    for (int r = 0; r < 4; ++r) {
      float v = oacc[dj][r] * inv[r];
      att[(size_t)(b*SEQ + qbase + lhi*4 + r)*DM + h*64 + dj*16 + lrow] = __float2bfloat16(v);
    }
  }
}

// ======================================================================================
extern "C" void kernel_launch(void* const* d_in, const int* in_sizes, int n_in,
                              void* d_out, int out_size, void* d_ws, size_t ws_size,
                              hipStream_t stream) {
  const float* x      = (const float*)d_in[0];
  const float* prior  = (const float*)d_in[2];
  const float* ga_g   = (const float*)d_in[3];
  const float* ga_b   = (const float*)d_in[4];
  const float* ga_wq  = (const float*)d_in[5];
  const float* ga_bq  = (const float*)d_in[6];
  const float* ga_wk  = (const float*)d_in[7];
  const float* ga_bk  = (const float*)d_in[8];
  const float* sa_wq  = (const float*)d_in[9];
  const float* sa_bq  = (const float*)d_in[10];
  const float* sa_wk  = (const float*)d_in[11];
  const float* sa_bk  = (const float*)d_in[12];
  const float* sa_wv  = (const float*)d_in[13];
  const float* sa_bv  = (const float*)d_in[14];
  const float* ff_w1  = (const float*)d_in[15];
  const float* ff_b1  = (const float*)d_in[16];
  const float* ff_w2  = (const float*)d_in[17];
  const float* ff_b2  = (const float*)d_in[18];
  const float* sl0_g  = (const float*)d_in[19];
  const float* sl0_b  = (const float*)d_in[20];
  const float* sl1_g  = (const float*)d_in[21];
  const float* sl1_b  = (const float*)d_in[22];

  float* out_x  = (float*)d_out;
  float* out_gp = out_x  + (size_t)MROWS*DM;
  float* out_bp = out_gp + (size_t)BH*SEQ*SEQ;

  char* W = (char*)d_ws;
  __hip_bfloat16* ln0    = (__hip_bfloat16*)(W + 0);          // 6.29 MB
  __hip_bfloat16* lnga   = (__hip_bfloat16*)(W + 6291456);    // 6.29 MB
  float* Qg   = (float*)(W + 12582912);                       // 12.58 MB
  float* Kg   = (float*)(W + 25165824);                       // 12.58 MB
  __hip_bfloat16* qkv3   = (__hip_bfloat16*)(W + 37748736);   // 18.87 MB [4096][2304]
  __hip_bfloat16* vT     = (__hip_bfloat16*)(W + 56623104);   // 6.29 MB
  __hip_bfloat16* attbuf = (__hip_bfloat16*)(W + 62914560);   // 6.29 MB
  __hip_bfloat16* ln1    = (__hip_bfloat16*)(W + 69206016);   // 6.29 MB
  __hip_bfloat16* wqkv   = (__hip_bfloat16*)(W + 75497472);   // 3.54 MB
  __hip_bfloat16* w1     = (__hip_bfloat16*)(W + 79036416);   // 4.72 MB
  __hip_bfloat16* w2     = (__hip_bfloat16*)(W + 83755008);   // 4.72 MB
  __hip_bfloat16* hbuf   = (__hip_bfloat16*)(W + 88473600);   // 25.17 MB [4096][3072]
  __hip_bfloat16* parts  = (__hip_bfloat16*)(W + 113639424);  // 25.17 MB (4 x 6.29)
  float* nsWS  = (float*)(W + 138805248);
  float* cumWS = (float*)(W + 139001856);

  // 1. dual pre-norm (both bf16) + weight conversions
  ln_cvt_kernel<<<7360, 256, 0, stream>>>(
      x, sl0_g, sl0_b, ln0, ga_g, ga_b, lnga,
      sa_wq, sa_wk, sa_wv, ff_w1, ff_w2, wqkv, w1, w2);
  // 2. QKV GEMM (V transposed in-epilogue) || GA q/k projection (role-split)
  gemm256_kernel<0><<<240, 512, 0, stream>>>(
      ln0, wqkv, sa_bq, sa_bk, sa_bv, qkv3, vT,
      nullptr, nullptr, nullptr, nullptr, nullptr,
      lnga, ga_wq, ga_bq, ga_wk, ga_bk, Qg, Kg);
  // 3. tridiagonal softmax -> ns + cum
  ga_edges_kernel<<<BH, SEQ, 0, stream>>>(Qg, Kg, prior, nsWS, cumWS);
  // 4. flash attention + writer rows [0,16384)
  attn_mfma_kernel<<<768 + 4096, 256, 0, stream>>>(
      qkv3, vT, cumWS, prior, attbuf, nsWS, out_gp, out_bp);
  // 5. residual + pre-norm for FFN (wave-per-row)
  ln_res_kernel<<<1024, 256, 0, stream>>>(x, attbuf, out_x, sl1_g, sl1_b, ln1);
  // 6. FFN1 GEMM + writer rows [16384,32768)
  gemm256_kernel<1><<<192 + 4096, 512, 0, stream>>>(
      ln1, w1, ff_b1, nullptr, nullptr, hbuf, nullptr,
      nsWS, cumWS, prior, out_gp, out_bp,
      nullptr, nullptr, nullptr, nullptr, nullptr, nullptr, nullptr);
  // 7. FFN2 split-K x4 + writer rows [32768,49152)
  gemm256_kernel<2><<<192 + 4096, 512, 0, stream>>>(
      hbuf, w2, nullptr, nullptr, nullptr, parts, nullptr,
      nsWS, cumWS, prior, out_gp, out_bp,
      nullptr, nullptr, nullptr, nullptr, nullptr, nullptr, nullptr);
  // 8. reduce partials + bias + residual
  ffn2_reduce_kernel<<<1536, 256, 0, stream>>>(parts, ff_b2, out_x);
}

// Round 12
// 233.094 us; speedup vs baseline: 1.4225x; 1.0006x over previous
//
#include <hip/hip_runtime.h>
#include <hip/hip_bf16.h>

#define HEADS 12
#define DM    768
#define DKH   64
#define DFF   3072
#define BSZ   8
#define SEQ   512
#define MROWS (BSZ*SEQ)   // 4096
#define BH    (BSZ*HEADS) // 96

typedef __attribute__((ext_vector_type(8))) short bf16x8;
typedef __attribute__((ext_vector_type(4))) float f32x4;

__device__ __forceinline__ void gload_lds16(const ushort* g, ushort* l) {
  __builtin_amdgcn_global_load_lds(
      (const __attribute__((address_space(1))) unsigned int*)g,
      (__attribute__((address_space(3))) unsigned int*)l, 16, 0, 0);
}

__device__ __forceinline__ float b2f(ushort u) {
  union { unsigned int i; float f; } c; c.i = (unsigned int)u << 16; return c.f;
}

// ---------------- gb-writer device fns (group/break prob rows) -------------------------
// 512-thr: 4 rows/block, 128 thr/row, 4 cols/thread
__device__ __forceinline__ void gb_rows_512(
    int row, int t, const float* __restrict__ nsWS, const float* __restrict__ cumWS,
    const float* __restrict__ prior, float* __restrict__ gp, float* __restrict__ bp) {
  int bh = row >> 9, q = row & 511;
  const float* cum = cumWS + (size_t)bh*SEQ;
  const float* ns  = nsWS  + (size_t)bh*SEQ;
  float pr = prior[0];
  float c0 = pr + (1.f - pr)*0.01f;
  float cq = cum[q];
  size_t rb = ((size_t)bh*SEQ + q)*SEQ;
  int k0 = (t & 127)*4;
  float4 g4, b4;
  float* gv = (float*)&g4; float* bv = (float*)&b4;
  #pragma unroll
  for (int j = 0; j < 4; ++j) {
    int k = k0 + j;
    float g;
    if (k == q) g = c0;
    else {
      float c = cum[k];
      g = __expf((k > q) ? (c - cq) : (cq - c)) + 1e-4f;
    }
    float bb = c0;
    if (k == q+1)      bb = ns[q];
    else if (k+1 == q) bb = ns[q-1];
    gv[j] = g; bv[j] = bb;
  }
  *(float4*)(gp + rb + k0) = g4;
  *(float4*)(bp + rb + k0) = b4;
}

// 256-thr: 4 rows/block, 64 thr/row, 8 cols/thread
__device__ __forceinline__ void gb_rows_256(
    int row, int t, const float* __restrict__ nsWS, const float* __restrict__ cumWS,
    const float* __restrict__ prior, float* __restrict__ gp, float* __restrict__ bp) {
  int bh = row >> 9, q = row & 511;
  const float* cum = cumWS + (size_t)bh*SEQ;
  const float* ns  = nsWS  + (size_t)bh*SEQ;
  float pr = prior[0];
  float c0 = pr + (1.f - pr)*0.01f;
  float cq = cum[q];
  size_t rb = ((size_t)bh*SEQ + q)*SEQ;
  int k0 = (t & 63)*8;
  float g8[8], b8[8];
  #pragma unroll
  for (int j = 0; j < 8; ++j) {
    int k = k0 + j;
    float g;
    if (k == q) g = c0;
    else {
      float c = cum[k];
      g = __expf((k > q) ? (c - cq) : (cq - c)) + 1e-4f;
    }
    float bb = c0;
    if (k == q+1)      bb = ns[q];
    else if (k+1 == q) bb = ns[q-1];
    g8[j] = g; b8[j] = bb;
  }
  *(float4*)(gp + rb + k0)     = *(float4*)&g8[0];
  *(float4*)(gp + rb + k0 + 4) = *(float4*)&g8[4];
  *(float4*)(bp + rb + k0)     = *(float4*)&b8[0];
  *(float4*)(bp + rb + k0 + 4) = *(float4*)&b8[4];
}

// ---------------- fused: dual pre-norm (both outputs bf16) + weight cvt ----------------
__global__ __launch_bounds__(256) void ln_cvt_kernel(
    const float* __restrict__ x,
    const float* __restrict__ g0, const float* __restrict__ b0, __hip_bfloat16* __restrict__ ln0,
    const float* __restrict__ gg, const float* __restrict__ gb, __hip_bfloat16* __restrict__ lnga,
    const float* __restrict__ swq, const float* __restrict__ swk, const float* __restrict__ swv,
    const float* __restrict__ w1s, const float* __restrict__ w2s,
    __hip_bfloat16* __restrict__ dqkv, __hip_bfloat16* __restrict__ d1,
    __hip_bfloat16* __restrict__ d2) {
  int t = threadIdx.x;
  if (blockIdx.x >= 1024) {
    long gid = (long)(blockIdx.x - 1024)*256 + t;
    long i = gid*4;
    const float* s; __hip_bfloat16* d; long off;
    if (i < 1769472L) {
      long j = i / 589824L; off = i - j*589824L;
      s = (j == 0) ? swq : (j == 1) ? swk : swv;
      d = dqkv + j*589824L;
    } else if (i < 4128768L) {
      off = i - 1769472L; s = w1s; d = d1;
    } else {
      off = i - 4128768L; s = w2s; d = d2;
    }
    float4 v = *(const float4*)(s + off);
    d[off+0] = __float2bfloat16(v.x);
    d[off+1] = __float2bfloat16(v.y);
    d[off+2] = __float2bfloat16(v.z);
    d[off+3] = __float2bfloat16(v.w);
    return;
  }
  int lane = t & 63, w = t >> 6;
  int row = blockIdx.x*4 + w;
  size_t base = (size_t)row * DM;
  float v[12]; float s = 0.f, s2 = 0.f;
  #pragma unroll
  for (int i = 0; i < 12; ++i) {
    v[i] = x[base + lane + 64*i];
    s += v[i]; s2 += v[i]*v[i];
  }
  #pragma unroll
  for (int off = 1; off < 64; off <<= 1) {
    s  += __shfl_xor(s,  off, 64);
    s2 += __shfl_xor(s2, off, 64);
  }
  float mean = s * (1.f/DM);
  float rstd = rsqrtf(s2 * (1.f/DM) - mean*mean + 1e-5f);
  #pragma unroll
  for (int i = 0; i < 12; ++i) {
    int c = lane + 64*i;
    float h = (v[i]-mean)*rstd;
    ln0[base + c]  = __float2bfloat16(h*g0[c] + b0[c]);
    lnga[base + c] = __float2bfloat16(h*gg[c] + gb[c]);
  }
}

// ---------------- tridiagonal softmax -> ns + prefix log-cumsum (wave scan) ------------
__global__ __launch_bounds__(512) void ga_edges_kernel(
    const float* __restrict__ Qg, const float* __restrict__ Kg,
    const float* __restrict__ prior, float* __restrict__ nsWS, float* __restrict__ cumWS) {
  __shared__ float pu[SEQ], pd[SEQ];
  __shared__ float wsum[8], wpre[8];
  int bh = blockIdx.x, m = threadIdx.x;
  const float* Qb = Qg + (size_t)bh*SEQ*DKH;
  const float* Kb = Kg + (size_t)bh*SEQ*DKH;
  const float4* qm = (const float4*)(Qb + (size_t)m*DKH);
  float su = -1e4f, sd = -1e4f;
  if (m < SEQ-1) {
    const float4* kn = (const float4*)(Kb + (size_t)(m+1)*DKH);
    float a = 0.f;
    #pragma unroll
    for (int i = 0; i < 16; ++i) {
      float4 q4 = qm[i], k4 = kn[i];
      a += q4.x*k4.x + q4.y*k4.y + q4.z*k4.z + q4.w*k4.w;
    }
    su = a * (1.f/DKH);
  }
  if (m >= 1) {
    const float4* kp = (const float4*)(Kb + (size_t)(m-1)*DKH);
    float a = 0.f;
    #pragma unroll
    for (int i = 0; i < 16; ++i) {
      float4 q4 = qm[i], k4 = kp[i];
      a += q4.x*k4.x + q4.y*k4.y + q4.z*k4.z + q4.w*k4.w;
    }
    sd = a * (1.f/DKH);
  }
  float mx = fmaxf(su, sd);
  float eu = __expf(su - mx), ed = __expf(sd - mx);
  float inv = 1.f / (eu + ed);
  pu[m] = eu * inv;
  pd[m] = ed * inv;
  __syncthreads();
  float pr = prior[0];
  float nsv = 0.f, lg = 0.f;
  if (m < SEQ-1) {
    float vv = sqrtf(pu[m]*pd[m+1] + 1e-4f);
    nsv = pr + (1.f - pr)*vv;
    lg = __logf(nsv + 1e-9f);
  }
  float v = lg;
  #pragma unroll
  for (int off = 1; off < 64; off <<= 1) {
    float u = __shfl_up(v, off, 64);
    if ((m & 63) >= off) v += u;
  }
  if ((m & 63) == 63) wsum[m >> 6] = v;
  __syncthreads();
  if (m == 0) {
    float a = 0.f;
    #pragma unroll
    for (int i = 0; i < 8; ++i) { wpre[i] = a; a += wsum[i]; }
  }
  __syncthreads();
  float incl = v + wpre[m >> 6];
  nsWS[(size_t)bh*SEQ + m] = nsv;
  cumWS[(size_t)bh*SEQ + m] = incl - lg;   // exclusive scan
}

// ---------------- 256x256 8-wave counted-vmcnt MFMA GEMM + fused roles -----------------
// MODE 0: QKV: q/k cols -> qkv3; V cols -> transposed into vT. Blocks [144,240): GA proj.
// MODE 1: FFN1 (bias+relu) + gb-writer rows [16384,32768). XCD = 4m x 6n rectangle.
// MODE 2: FFN2 split-K x4 + gb-writer rows [32768,49152). XCD owns one z, 8m x 3n rect.
template<int MODE>
__global__ __launch_bounds__(512, 2) void gemm256_kernel(
    const __hip_bfloat16* __restrict__ A, const __hip_bfloat16* __restrict__ B,
    const float* __restrict__ b0, const float* __restrict__ b1, const float* __restrict__ b2,
    __hip_bfloat16* __restrict__ C, __hip_bfloat16* __restrict__ vT,
    const float* __restrict__ nsWS, const float* __restrict__ cumWS,
    const float* __restrict__ prior, float* __restrict__ gp, float* __restrict__ bp,
    const __hip_bfloat16* __restrict__ lnga,
    const float* __restrict__ gwq, const float* __restrict__ gbq,
    const float* __restrict__ gwk, const float* __restrict__ gbk,
    float* __restrict__ Qg, float* __restrict__ Kg) {
  constexpr int N    = (MODE==0) ? 2304 : (MODE==1) ? 3072 : 768;
  constexpr int TN   = N / 256;
  constexpr int LDAB = (MODE==2) ? 3072 : 768;
  constexpr int NT   = (MODE==0) ? 144 : 192;
  __shared__ ushort LDS[65536];          // 128 KB
  int t = threadIdx.x;
  int bidx = blockIdx.x;
  if (bidx >= NT) {
    if (MODE == 0) {
      // ---- GA q/k projection: 2 tasks (h, 256-row chunk) per block ----
      ushort* WQ = LDS;                  // [64][72]
      ushort* WK = LDS + 4608;
      for (int i = t; i < 4096; i += 512) {
        int d = i >> 6, c = i & 63;
        __hip_bfloat16 q = __float2bfloat16(gwq[i]);
        __hip_bfloat16 k = __float2bfloat16(gwk[i]);
        WQ[d*72 + c] = *(ushort*)&q;
        WK[d*72 + c] = *(ushort*)&k;
      }
      __syncthreads();
      int task = (bidx - 144)*2 + (t >> 8);
      int h  = task >> 4;
      int r0 = (task & 15) * 256;
      int t2 = t & 255;
      int lane = t2 & 63, w = t2 >> 6;
      int lrow = lane & 15, lhi = lane >> 4;
      const ushort* Ag2 = (const ushort*)lnga;
      bf16x8 a[4][2];
      #pragma unroll
      for (int i = 0; i < 4; ++i)
        #pragma unroll
        for (int ks = 0; ks < 2; ++ks)
          a[i][ks] = *(const bf16x8*)(Ag2 + (size_t)(r0 + w*64 + i*16 + lrow)*DM + h*64 + ks*32 + lhi*8);
      int b = r0 >> 9;
      #pragma unroll
      for (int qk = 0; qk < 2; ++qk) {
        const ushort* Wm = qk ? WK : WQ;
        const float* bias = qk ? gbk : gbq;
        float* Og = qk ? Kg : Qg;
        bf16x8 bf[4][2];
        #pragma unroll
        for (int j = 0; j < 4; ++j)
          #pragma unroll
          for (int ks = 0; ks < 2; ++ks)
            bf[j][ks] = *(const bf16x8*)&Wm[(j*16 + lrow)*72 + ks*32 + lhi*8];
        f32x4 acc[4][4] = {};
        #pragma unroll
        for (int i = 0; i < 4; ++i)
          #pragma unroll
          for (int j = 0; j < 4; ++j) {
            acc[i][j] = __builtin_amdgcn_mfma_f32_16x16x32_bf16(a[i][0], bf[j][0], acc[i][j], 0, 0, 0);
            acc[i][j] = __builtin_amdgcn_mfma_f32_16x16x32_bf16(a[i][1], bf[j][1], acc[i][j], 0, 0, 0);
          }
        #pragma unroll
        for (int i = 0; i < 4; ++i) {
          int rowb = r0 + w*64 + i*16 + lhi*4;
          #pragma unroll
          for (int j = 0; j < 4; ++j) {
            int d = j*16 + lrow;
            float bv = bias[d];
            #pragma unroll
            for (int r = 0; r < 4; ++r) {
              int sIdx = (rowb + r) & 511;
              Og[(((size_t)b*HEADS + h)*SEQ + sIdx)*DKH + d] = acc[i][j][r] + bv;
            }
          }
        }
      }
    } else {
      // ---- gb writer: 4 q-rows per block (hides on the ~64 CUs the GEMM leaves idle) --
      int base = (MODE == 1) ? 16384 : 32768;
      int row = base + (bidx - NT)*4 + (t >> 7);
      gb_rows_512(row, t, nsWS, cumWS, prior, gp, bp);
    }
    return;
  }
  int lane = t & 63, w = t >> 6;
  int rin = lane >> 3, gr = lane & 7;
  int lrow = lane & 15, lhi = lane >> 4;
  // ---- XCD-footprint-shaped tile mapping (bijective; XCD = bidx & 7 heuristic) ----
  int z = 0, mtile, ntile;
  if (MODE == 0) {
    int tile = (bidx & 7)*18 + (bidx >> 3);     // 2m x 9n per XCD (~4.2 MB)
    mtile = tile / TN; ntile = tile % TN;
  } else if (MODE == 1) {
    int xq = bidx & 7, i = bidx >> 3;           // 4m x 6n per XCD (3.8 MB, fits L2)
    mtile = (xq & 3)*4 + i/6;
    ntile = (xq >> 2)*6 + i%6;
  } else {
    int xq = bidx & 7, i = bidx >> 3;           // one z per XCD-pair; 8m x 3n (4.2 MB)
    z = xq >> 1;
    int tl = (xq & 1)*24 + i;
    mtile = tl / 3; ntile = tl % 3;
  }
  int m0 = mtile * 256;
  int n0 = ntile * 256;
  int kOff = (MODE == 2) ? z * 768 : 0;
  if (MODE == 2) C += (size_t)z * MROWS * 768;
  int wr = w >> 2, wc = w & 3;
  const ushort* Ag = (const ushort*)A;
  const ushort* Bg = (const ushort*)B;
  f32x4 acc[8][4] = {};
  // LDS content swizzle via pre-swizzled GLOBAL source (dest stays linear).
  auto STAGE = [&](int p, int kt) {
    int k0 = kOff + kt*64;
    ushort* Ad = &LDS[p*16384];
    ushort* Bd = &LDS[32768 + p*16384];
    int cs = (gr ^ rin) * 8;
    #pragma unroll
    for (int q = 0; q < 4; ++q) {
      int rr = q*64 + w*8 + rin;               // rr & 7 == rin
      gload_lds16(Ag + (size_t)(m0 + rr)*LDAB + k0 + cs, &Ad[(q*64 + w*8)*64]);
      gload_lds16(Bg + (size_t)(n0 + rr)*LDAB + k0 + cs, &Bd[(q*64 + w*8)*64]);
    }
  };
  const int nt = 12;                            // K = 768, BK = 64
  STAGE(0, 0);
  STAGE(1, 1);
  asm volatile("s_waitcnt vmcnt(8)" ::: "memory");   // tile 0 landed (tile 1 in flight)
  __builtin_amdgcn_s_barrier();
  int p = 0;
  for (int kt = 0; kt < nt; ++kt) {
    const ushort* Ar = &LDS[p*16384];
    const ushort* Br = &LDS[32768 + p*16384];
    int sw0 = (lhi ^ (lrow & 7)) * 8;           // ks=0: granule lhi
    int sw1 = ((4 + lhi) ^ (lrow & 7)) * 8;     // ks=1: granule 4+lhi
    bf16x8 a0[8], b0r[4], a1[8], b1r[4];
    #pragma unroll
    for (int i = 0; i < 8; ++i)
      a0[i] = *(const bf16x8*)&Ar[(wr*128 + i*16 + lrow)*64 + sw0];
    #pragma unroll
    for (int j = 0; j < 4; ++j)
      b0r[j] = *(const bf16x8*)&Br[(wc*64 + j*16 + lrow)*64 + sw0];
    #pragma unroll
    for (int i = 0; i < 8; ++i)
      #pragma unroll
      for (int j = 0; j < 4; ++j)
        acc[i][j] = __builtin_amdgcn_mfma_f32_16x16x32_bf16(a0[i], b0r[j], acc[i][j], 0, 0, 0);
    #pragma unroll
    for (int i = 0; i < 8; ++i)
      a1[i] = *(const bf16x8*)&Ar[(wr*128 + i*16 + lrow)*64 + sw1];
    #pragma unroll
    for (int j = 0; j < 4; ++j)
      b1r[j] = *(const bf16x8*)&Br[(wc*64 + j*16 + lrow)*64 + sw1];
    asm volatile("s_waitcnt lgkmcnt(0)" ::: "memory");  // all our LDS reads complete
    __builtin_amdgcn_sched_barrier(0);
    __builtin_amdgcn_s_barrier();               // every wave done reading buf p
    if (kt + 2 < nt) STAGE(p, kt + 2);          // safe: clobbers fully-consumed buffer
    __builtin_amdgcn_s_setprio(1);
    #pragma unroll
    for (int i = 0; i < 8; ++i)
      #pragma unroll
      for (int j = 0; j < 4; ++j)
        acc[i][j] = __builtin_amdgcn_mfma_f32_16x16x32_bf16(a1[i], b1r[j], acc[i][j], 0, 0, 0);
    __builtin_amdgcn_s_setprio(0);
    if (kt + 1 < nt) {
      if (kt + 2 < nt) asm volatile("s_waitcnt vmcnt(8)" ::: "memory");  // next tile landed
      else             asm volatile("s_waitcnt vmcnt(0)" ::: "memory");
      __builtin_amdgcn_s_barrier();
    }
    p ^= 1;
  }
  // ---- epilogue ----
  if (MODE == 0 && n0 >= 1536) {
    // V tile: bias + transpose via two-pass LDS bounce -> vT[bh][d][s]
    ushort* T = LDS;                      // [128][264] per pass
    int b = m0 >> 9, s0 = m0 & 511;
    #pragma unroll
    for (int ps = 0; ps < 2; ++ps) {
      if ((wc >> 1) == ps) {
        #pragma unroll
        for (int j = 0; j < 4; ++j) {
          int dl = (wc & 1)*64 + j*16 + lrow;
          float bvv = b2[n0 - 1536 + ps*128 + dl];
          #pragma unroll
          for (int i = 0; i < 8; ++i) {
            #pragma unroll
            for (int r = 0; r < 4; ++r) {
              __hip_bfloat16 hh = __float2bfloat16(acc[i][j][r] + bvv);
              T[dl*264 + wr*128 + i*16 + lhi*4 + r] = *(ushort*)&hh;
            }
          }
        }
      }
      __syncthreads();
      #pragma unroll
      for (int it = 0; it < 8; ++it) {
        int idx = t + 512*it;
        int dl = idx >> 5, sc8 = (idx & 31)*8;
        int dg = n0 - 1536 + ps*128 + dl;
        int h = dg >> 6, dmod = dg & 63;
        bf16x8 vv = *(const bf16x8*)&T[dl*264 + sc8];
        *(bf16x8*)((ushort*)vT + ((size_t)(b*HEADS + h)*64 + dmod)*512 + s0 + sc8) = vv;
      }
      __syncthreads();
    }
    return;
  }
  #pragma unroll
  for (int i = 0; i < 8; ++i) {
    int grow = m0 + wr*128 + i*16 + lhi*4;
    #pragma unroll
    for (int j = 0; j < 4; ++j) {
      int gcol = n0 + wc*64 + j*16 + lrow;
      float bvv;
      if (MODE == 0)      bvv = (gcol < 768) ? b0[gcol] : b1[gcol-768];
      else if (MODE == 1) bvv = b0[gcol];
      else                bvv = 0.f;
      #pragma unroll
      for (int r = 0; r < 4; ++r) {
        float v = acc[i][j][r] + bvv;
        if (MODE == 1) v = fmaxf(v, 0.f);
        C[(size_t)(grow + r)*N + gcol] = __float2bfloat16(v);
      }
    }
  }
}

// ---------------- FFN2 reduce: out += bias + sum of 4 bf16 partials --------------------
__global__ __launch_bounds__(256) void ffn2_reduce_kernel(
    const __hip_bfloat16* __restrict__ p, const float* __restrict__ bias,
    float* __restrict__ out) {
  int gid = blockIdx.x*256 + threadIdx.x;
  size_t i = (size_t)gid*8;
  const ushort* pp = (const ushort*)p;
  float acc[8];
  int col = (int)(i % DM);
  #pragma unroll
  for (int j = 0; j < 8; ++j) acc[j] = bias[col + j];
  #pragma unroll
  for (int s = 0; s < 4; ++s) {
    bf16x8 v = *(const bf16x8*)(pp + (size_t)s*MROWS*DM + i);
    #pragma unroll
    for (int j = 0; j < 8; ++j) acc[j] += b2f((ushort)v[j]);
  }
  float4 o0 = *(const float4*)(out + i);
  float4 o1 = *(const float4*)(out + i + 4);
  o0.x += acc[0]; o0.y += acc[1]; o0.z += acc[2]; o0.w += acc[3];
  o1.x += acc[4]; o1.y += acc[5]; o1.z += acc[6]; o1.w += acc[7];
  *(float4*)(out + i)     = o0;
  *(float4*)(out + i + 4) = o1;
}

// ---------------- residual add + LN (wave-per-row) -------------------------------------
__global__ __launch_bounds__(256) void ln_res_kernel(
    const float* __restrict__ x, const __hip_bfloat16* __restrict__ a, float* __restrict__ xs,
    const float* __restrict__ g, const float* __restrict__ b, __hip_bfloat16* __restrict__ o) {
  int t = threadIdx.x;
  int lane = t & 63, w = t >> 6;
  int row = blockIdx.x*4 + w;
  size_t base = (size_t)row * DM;
  const ushort* ab = (const ushort*)a;
  float v[12]; float s = 0.f, s2 = 0.f;
  #pragma unroll
  for (int i = 0; i < 12; ++i) {
    int c = lane + 64*i;
    v[i] = x[base + c] + b2f(ab[base + c]);
    xs[base + c] = v[i];
    s += v[i]; s2 += v[i]*v[i];
  }
  #pragma unroll
  for (int off = 1; off < 64; off <<= 1) {
    s  += __shfl_xor(s,  off, 64);
    s2 += __shfl_xor(s2, off, 64);
  }
  float mean = s * (1.f/DM);
  float rstd = rsqrtf(s2 * (1.f/DM) - mean*mean + 1e-5f);
  #pragma unroll
  for (int i = 0; i < 12; ++i) {
    int c = lane + 64*i;
    o[base + c] = __float2bfloat16((v[i]-mean)*rstd*g[c] + b[c]);
  }
}

// ---------------- MFMA flash attention + gb-writer blocks ------------------------------
__global__ __launch_bounds__(256) void attn_mfma_kernel(
    const __hip_bfloat16* __restrict__ qk, const __hip_bfloat16* __restrict__ vT,
    const float* __restrict__ cumWS, const float* __restrict__ prior,
    __hip_bfloat16* __restrict__ att,
    const float* __restrict__ nsWS, float* __restrict__ gp, float* __restrict__ bp) {
  __shared__ ushort Ps[4][16][72];
  int t = threadIdx.x;
  int bidx = blockIdx.x;
  if (bidx >= 768) {
    int row = (bidx - 768)*4 + (t >> 6);   // rows [0, 16384)
    gb_rows_256(row, t, nsWS, cumWS, prior, gp, bp);
    return;
  }
  int lane = t & 63, wid = t >> 6;
  int tile = (bidx & 7)*96 + (bidx >> 3);
  int qt = tile & 7, bh = tile >> 3;
  int b = bh / HEADS, h = bh % HEADS;
  int lrow = lane & 15, lhi = lane >> 4;
  int qbase = qt*64 + wid*16;
  const ushort* qg = (const ushort*)qk;
  bf16x8 aq[2];
  {
    const ushort* qp = qg + (size_t)(b*SEQ + qbase + lrow)*2304 + h*64 + lhi*8;
    aq[0] = *(const bf16x8*)qp;
    aq[1] = *(const bf16x8*)(qp + 32);
  }
  const float* cum = cumWS + (size_t)bh*SEQ;
  float pr = prior[0];
  float c0 = pr + (1.f - pr)*0.01f;
  int qrow[4]; float cq[4];
  #pragma unroll
  for (int r = 0; r < 4; ++r) { qrow[r] = qbase + lhi*4 + r; cq[r] = cum[qrow[r]]; }
  float lsum[4] = {0.f, 0.f, 0.f, 0.f};
  f32x4 oacc[4] = {};
  const ushort* kg = qg + 768;
  const ushort* vg = (const ushort*)vT;
  for (int kt = 0; kt < 8; ++kt) {
    f32x4 sacc[4] = {};
    #pragma unroll
    for (int j = 0; j < 4; ++j) {
      const ushort* kp = kg + (size_t)(b*SEQ + kt*64 + j*16 + lrow)*2304 + h*64 + lhi*8;
      bf16x8 bk0 = *(const bf16x8*)kp;
      bf16x8 bk1 = *(const bf16x8*)(kp + 32);
      sacc[j] = __builtin_amdgcn_mfma_f32_16x16x32_bf16(aq[0], bk0, sacc[j], 0, 0, 0);
      sacc[j] = __builtin_amdgcn_mfma_f32_16x16x32_bf16(aq[1], bk1, sacc[j], 0, 0, 0);
    }
    float ck[4];
    #pragma unroll
    for (int j = 0; j < 4; ++j) ck[j] = cum[kt*64 + j*16 + lrow];
    #pragma unroll
    for (int j = 0; j < 4; ++j) {
      int kk = kt*64 + j*16 + lrow;
      #pragma unroll
      for (int r = 0; r < 4; ++r) {
        float e = __expf(fminf(sacc[j][r]*0.125f - 16.f, 60.f));
        lsum[r] += e;
        float dd = ck[j] - cq[r];
        float gpv = (kk == qrow[r]) ? c0 : (__expf((kk > qrow[r]) ? dd : -dd) + 1e-4f);
        __hip_bfloat16 pb = __float2bfloat16(e * gpv);
        Ps[wid][lhi*4 + r][j*16 + lrow] = *(ushort*)&pb;
      }
    }
    asm volatile("s_waitcnt lgkmcnt(0)" ::: "memory");
    __builtin_amdgcn_s_setprio(1);
    #pragma unroll
    for (int c = 0; c < 2; ++c) {
      bf16x8 ap = *(const bf16x8*)&Ps[wid][lrow][c*32 + lhi*8];
      #pragma unroll
      for (int dj = 0; dj < 4; ++dj) {
        const ushort* vp = vg + ((size_t)bh*64 + dj*16 + lrow)*512 + kt*64 + c*32 + lhi*8;
        bf16x8 bv = *(const bf16x8*)vp;
        oacc[dj] = __builtin_amdgcn_mfma_f32_16x16x32_bf16(ap, bv, oacc[dj], 0, 0, 0);
      }
    }
    __builtin_amdgcn_s_setprio(0);
  }
  #pragma unroll
  for (int off = 1; off < 16; off <<= 1) {
    #pragma unroll
    for (int r = 0; r < 4; ++r) lsum[r] += __shfl_xor(lsum[r], off, 64);
  }
  float inv[4];
  #pragma unroll
  for (int r = 0; r < 4; ++r) inv[r] = 1.f / lsum[r];
  #pragma unroll
  for (int dj = 0; dj < 4; ++dj) {
    #pragma unroll
    for (int r = 0; r < 4; ++r) {
      float v = oacc[dj][r] * inv[r];
      att[(size_t)(b*SEQ + qbase + lhi*4 + r)*DM + h*64 + dj*16 + lrow] = __float2bfloat16(v);
    }
  }
}

// ======================================================================================
extern "C" void kernel_launch(void* const* d_in, const int* in_sizes, int n_in,
                              void* d_out, int out_size, void* d_ws, size_t ws_size,
                              hipStream_t stream) {
  const float* x      = (const float*)d_in[0];
  const float* prior  = (const float*)d_in[2];
  const float* ga_g   = (const float*)d_in[3];
  const float* ga_b   = (const float*)d_in[4];
  const float* ga_wq  = (const float*)d_in[5];
  const float* ga_bq  = (const float*)d_in[6];
  const float* ga_wk  = (const float*)d_in[7];
  const float* ga_bk  = (const float*)d_in[8];
  const float* sa_wq  = (const float*)d_in[9];
  const float* sa_bq  = (const float*)d_in[10];
  const float* sa_wk  = (const float*)d_in[11];
  const float* sa_bk  = (const float*)d_in[12];
  const float* sa_wv  = (const float*)d_in[13];
  const float* sa_bv  = (const float*)d_in[14];
  const float* ff_w1  = (const float*)d_in[15];
  const float* ff_b1  = (const float*)d_in[16];
  const float* ff_w2  = (const float*)d_in[17];
  const float* ff_b2  = (const float*)d_in[18];
  const float* sl0_g  = (const float*)d_in[19];
  const float* sl0_b  = (const float*)d_in[20];
  const float* sl1_g  = (const float*)d_in[21];
  const float* sl1_b  = (const float*)d_in[22];

  float* out_x  = (float*)d_out;
  float* out_gp = out_x  + (size_t)MROWS*DM;
  float* out_bp = out_gp + (size_t)BH*SEQ*SEQ;

  char* W = (char*)d_ws;
  __hip_bfloat16* ln0    = (__hip_bfloat16*)(W + 0);          // 6.29 MB
  __hip_bfloat16* lnga   = (__hip_bfloat16*)(W + 6291456);    // 6.29 MB
  float* Qg   = (float*)(W + 12582912);                       // 12.58 MB
  float* Kg   = (float*)(W + 25165824);                       // 12.58 MB
  __hip_bfloat16* qkv3   = (__hip_bfloat16*)(W + 37748736);   // 18.87 MB [4096][2304]
  __hip_bfloat16* vT     = (__hip_bfloat16*)(W + 56623104);   // 6.29 MB
  __hip_bfloat16* attbuf = (__hip_bfloat16*)(W + 62914560);   // 6.29 MB
  __hip_bfloat16* ln1    = (__hip_bfloat16*)(W + 69206016);   // 6.29 MB
  __hip_bfloat16* wqkv   = (__hip_bfloat16*)(W + 75497472);   // 3.54 MB
  __hip_bfloat16* w1     = (__hip_bfloat16*)(W + 79036416);   // 4.72 MB
  __hip_bfloat16* w2     = (__hip_bfloat16*)(W + 83755008);   // 4.72 MB
  __hip_bfloat16* hbuf   = (__hip_bfloat16*)(W + 88473600);   // 25.17 MB [4096][3072]
  __hip_bfloat16* parts  = (__hip_bfloat16*)(W + 113639424);  // 25.17 MB (4 x 6.29)
  float* nsWS  = (float*)(W + 138805248);
  float* cumWS = (float*)(W + 139001856);

  // 1. dual pre-norm (both bf16) + weight conversions
  ln_cvt_kernel<<<7360, 256, 0, stream>>>(
      x, sl0_g, sl0_b, ln0, ga_g, ga_b, lnga,
      sa_wq, sa_wk, sa_wv, ff_w1, ff_w2, wqkv, w1, w2);
  // 2. QKV GEMM (V transposed in-epilogue) || GA q/k projection (role-split)
  gemm256_kernel<0><<<240, 512, 0, stream>>>(
      ln0, wqkv, sa_bq, sa_bk, sa_bv, qkv3, vT,
      nullptr, nullptr, nullptr, nullptr, nullptr,
      lnga, ga_wq, ga_bq, ga_wk, ga_bk, Qg, Kg);
  // 3. tridiagonal softmax -> ns + cum
  ga_edges_kernel<<<BH, SEQ, 0, stream>>>(Qg, Kg, prior, nsWS, cumWS);
  // 4. flash attention + writer rows [0,16384)
  attn_mfma_kernel<<<768 + 4096, 256, 0, stream>>>(
      qkv3, vT, cumWS, prior, attbuf, nsWS, out_gp, out_bp);
  // 5. residual + pre-norm for FFN (wave-per-row)
  ln_res_kernel<<<1024, 256, 0, stream>>>(x, attbuf, out_x, sl1_g, sl1_b, ln1);
  // 6. FFN1 GEMM + writer rows [16384,32768)
  gemm256_kernel<1><<<192 + 4096, 512, 0, stream>>>(
      ln1, w1, ff_b1, nullptr, nullptr, hbuf, nullptr,
      nsWS, cumWS, prior, out_gp, out_bp,
      nullptr, nullptr, nullptr, nullptr, nullptr, nullptr, nullptr);
  // 7. FFN2 split-K x4 + writer rows [32768,49152)
  gemm256_kernel<2><<<192 + 4096, 512, 0, stream>>>(
      hbuf, w2, nullptr, nullptr, nullptr, parts, nullptr,
      nsWS, cumWS, prior, out_gp, out_bp,
      nullptr, nullptr, nullptr, nullptr, nullptr, nullptr, nullptr);
  // 8. reduce partials + bias + residual
  ffn2_reduce_kernel<<<1536, 256, 0, stream>>>(parts, ff_b2, out_x);
}

// Round 13
// 232.060 us; speedup vs baseline: 1.4288x; 1.0045x over previous
//
#include <hip/hip_runtime.h>
#include <hip/hip_bf16.h>

#define HEADS 12
#define DM    768
#define DKH   64
#define DFF   3072
#define BSZ   8
#define SEQ   512
#define MROWS (BSZ*SEQ)   // 4096
#define BH    (BSZ*HEADS) // 96

typedef __attribute__((ext_vector_type(8))) short bf16x8;
typedef __attribute__((ext_vector_type(4))) float f32x4;

__device__ __forceinline__ void gload_lds16(const ushort* g, ushort* l) {
  __builtin_amdgcn_global_load_lds(
      (const __attribute__((address_space(1))) unsigned int*)g,
      (__attribute__((address_space(3))) unsigned int*)l, 16, 0, 0);
}

__device__ __forceinline__ float b2f(ushort u) {
  union { unsigned int i; float f; } c; c.i = (unsigned int)u << 16; return c.f;
}

// ---------------- gb-writer device fns (group/break prob rows) -------------------------
// 512-thr: 4 rows/block, 128 thr/row, 4 cols/thread
__device__ __forceinline__ void gb_rows_512(
    int row, int t, const float* __restrict__ nsWS, const float* __restrict__ cumWS,
    const float* __restrict__ prior, float* __restrict__ gp, float* __restrict__ bp) {
  int bh = row >> 9, q = row & 511;
  const float* cum = cumWS + (size_t)bh*SEQ;
  const float* ns  = nsWS  + (size_t)bh*SEQ;
  float pr = prior[0];
  float c0 = pr + (1.f - pr)*0.01f;
  float cq = cum[q];
  size_t rb = ((size_t)bh*SEQ + q)*SEQ;
  int k0 = (t & 127)*4;
  float4 g4, b4;
  float* gv = (float*)&g4; float* bv = (float*)&b4;
  #pragma unroll
  for (int j = 0; j < 4; ++j) {
    int k = k0 + j;
    float g;
    if (k == q) g = c0;
    else {
      float c = cum[k];
      g = __expf((k > q) ? (c - cq) : (cq - c)) + 1e-4f;
    }
    float bb = c0;
    if (k == q+1)      bb = ns[q];
    else if (k+1 == q) bb = ns[q-1];
    gv[j] = g; bv[j] = bb;
  }
  *(float4*)(gp + rb + k0) = g4;
  *(float4*)(bp + rb + k0) = b4;
}

// 256-thr: 4 rows/block, 64 thr/row, 8 cols/thread
__device__ __forceinline__ void gb_rows_256(
    int row, int t, const float* __restrict__ nsWS, const float* __restrict__ cumWS,
    const float* __restrict__ prior, float* __restrict__ gp, float* __restrict__ bp) {
  int bh = row >> 9, q = row & 511;
  const float* cum = cumWS + (size_t)bh*SEQ;
  const float* ns  = nsWS  + (size_t)bh*SEQ;
  float pr = prior[0];
  float c0 = pr + (1.f - pr)*0.01f;
  float cq = cum[q];
  size_t rb = ((size_t)bh*SEQ + q)*SEQ;
  int k0 = (t & 63)*8;
  float g8[8], b8[8];
  #pragma unroll
  for (int j = 0; j < 8; ++j) {
    int k = k0 + j;
    float g;
    if (k == q) g = c0;
    else {
      float c = cum[k];
      g = __expf((k > q) ? (c - cq) : (cq - c)) + 1e-4f;
    }
    float bb = c0;
    if (k == q+1)      bb = ns[q];
    else if (k+1 == q) bb = ns[q-1];
    g8[j] = g; b8[j] = bb;
  }
  *(float4*)(gp + rb + k0)     = *(float4*)&g8[0];
  *(float4*)(gp + rb + k0 + 4) = *(float4*)&g8[4];
  *(float4*)(bp + rb + k0)     = *(float4*)&b8[0];
  *(float4*)(bp + rb + k0 + 4) = *(float4*)&b8[4];
}

// ---------------- fused: dual pre-norm (both outputs bf16) + weight cvt ----------------
__global__ __launch_bounds__(256) void ln_cvt_kernel(
    const float* __restrict__ x,
    const float* __restrict__ g0, const float* __restrict__ b0, __hip_bfloat16* __restrict__ ln0,
    const float* __restrict__ gg, const float* __restrict__ gb, __hip_bfloat16* __restrict__ lnga,
    const float* __restrict__ swq, const float* __restrict__ swk, const float* __restrict__ swv,
    const float* __restrict__ w1s, const float* __restrict__ w2s,
    __hip_bfloat16* __restrict__ dqkv, __hip_bfloat16* __restrict__ d1,
    __hip_bfloat16* __restrict__ d2) {
  int t = threadIdx.x;
  if (blockIdx.x >= 1024) {
    long gid = (long)(blockIdx.x - 1024)*256 + t;
    long i = gid*4;
    const float* s; __hip_bfloat16* d; long off;
    if (i < 1769472L) {
      long j = i / 589824L; off = i - j*589824L;
      s = (j == 0) ? swq : (j == 1) ? swk : swv;
      d = dqkv + j*589824L;
    } else if (i < 4128768L) {
      off = i - 1769472L; s = w1s; d = d1;
    } else {
      off = i - 4128768L; s = w2s; d = d2;
    }
    float4 v = *(const float4*)(s + off);
    d[off+0] = __float2bfloat16(v.x);
    d[off+1] = __float2bfloat16(v.y);
    d[off+2] = __float2bfloat16(v.z);
    d[off+3] = __float2bfloat16(v.w);
    return;
  }
  int lane = t & 63, w = t >> 6;
  int row = blockIdx.x*4 + w;
  size_t base = (size_t)row * DM;
  float v[12]; float s = 0.f, s2 = 0.f;
  #pragma unroll
  for (int i = 0; i < 12; ++i) {
    v[i] = x[base + lane + 64*i];
    s += v[i]; s2 += v[i]*v[i];
  }
  #pragma unroll
  for (int off = 1; off < 64; off <<= 1) {
    s  += __shfl_xor(s,  off, 64);
    s2 += __shfl_xor(s2, off, 64);
  }
  float mean = s * (1.f/DM);
  float rstd = rsqrtf(s2 * (1.f/DM) - mean*mean + 1e-5f);
  #pragma unroll
  for (int i = 0; i < 12; ++i) {
    int c = lane + 64*i;
    float h = (v[i]-mean)*rstd;
    ln0[base + c]  = __float2bfloat16(h*g0[c] + b0[c]);
    lnga[base + c] = __float2bfloat16(h*gg[c] + gb[c]);
  }
}

// ---------------- tridiagonal softmax -> ns + prefix log-cumsum (wave scan) ------------
__global__ __launch_bounds__(512) void ga_edges_kernel(
    const float* __restrict__ Qg, const float* __restrict__ Kg,
    const float* __restrict__ prior, float* __restrict__ nsWS, float* __restrict__ cumWS) {
  __shared__ float pu[SEQ], pd[SEQ];
  __shared__ float wsum[8], wpre[8];
  int bh = blockIdx.x, m = threadIdx.x;
  const float* Qb = Qg + (size_t)bh*SEQ*DKH;
  const float* Kb = Kg + (size_t)bh*SEQ*DKH;
  const float4* qm = (const float4*)(Qb + (size_t)m*DKH);
  float su = -1e4f, sd = -1e4f;
  if (m < SEQ-1) {
    const float4* kn = (const float4*)(Kb + (size_t)(m+1)*DKH);
    float a = 0.f;
    #pragma unroll
    for (int i = 0; i < 16; ++i) {
      float4 q4 = qm[i], k4 = kn[i];
      a += q4.x*k4.x + q4.y*k4.y + q4.z*k4.z + q4.w*k4.w;
    }
    su = a * (1.f/DKH);
  }
  if (m >= 1) {
    const float4* kp = (const float4*)(Kb + (size_t)(m-1)*DKH);
    float a = 0.f;
    #pragma unroll
    for (int i = 0; i < 16; ++i) {
      float4 q4 = qm[i], k4 = kp[i];
      a += q4.x*k4.x + q4.y*k4.y + q4.z*k4.z + q4.w*k4.w;
    }
    sd = a * (1.f/DKH);
  }
  float mx = fmaxf(su, sd);
  float eu = __expf(su - mx), ed = __expf(sd - mx);
  float inv = 1.f / (eu + ed);
  pu[m] = eu * inv;
  pd[m] = ed * inv;
  __syncthreads();
  float pr = prior[0];
  float nsv = 0.f, lg = 0.f;
  if (m < SEQ-1) {
    float vv = sqrtf(pu[m]*pd[m+1] + 1e-4f);
    nsv = pr + (1.f - pr)*vv;
    lg = __logf(nsv + 1e-9f);
  }
  float v = lg;
  #pragma unroll
  for (int off = 1; off < 64; off <<= 1) {
    float u = __shfl_up(v, off, 64);
    if ((m & 63) >= off) v += u;
  }
  if ((m & 63) == 63) wsum[m >> 6] = v;
  __syncthreads();
  if (m == 0) {
    float a = 0.f;
    #pragma unroll
    for (int i = 0; i < 8; ++i) { wpre[i] = a; a += wsum[i]; }
  }
  __syncthreads();
  float incl = v + wpre[m >> 6];
  nsWS[(size_t)bh*SEQ + m] = nsv;
  cumWS[(size_t)bh*SEQ + m] = incl - lg;   // exclusive scan
}

// ---------------- 256x256 8-wave MFMA GEMM, fine-phase schedule + fused roles ----------
// MODE 0: QKV: q/k cols -> qkv3; V cols -> transposed into vT. Blocks [144,240): GA proj.
// MODE 1: FFN1 (bias+relu) + gb-writer rows [16384,32768)
// MODE 2: FFN2 split-K x4 + gb-writer rows [32768,49152)
template<int MODE>
__global__ __launch_bounds__(512, 2) void gemm256_kernel(
    const __hip_bfloat16* __restrict__ A, const __hip_bfloat16* __restrict__ B,
    const float* __restrict__ b0, const float* __restrict__ b1, const float* __restrict__ b2,
    __hip_bfloat16* __restrict__ C, __hip_bfloat16* __restrict__ vT,
    const float* __restrict__ nsWS, const float* __restrict__ cumWS,
    const float* __restrict__ prior, float* __restrict__ gp, float* __restrict__ bp,
    const __hip_bfloat16* __restrict__ lnga,
    const float* __restrict__ gwq, const float* __restrict__ gbq,
    const float* __restrict__ gwk, const float* __restrict__ gbk,
    float* __restrict__ Qg, float* __restrict__ Kg) {
  constexpr int N    = (MODE==0) ? 2304 : (MODE==1) ? 3072 : 768;
  constexpr int TN   = N / 256;
  constexpr int LDAB = (MODE==2) ? 3072 : 768;
  constexpr int NT   = (MODE==0) ? 144 : 192;
  __shared__ ushort LDS[65536];          // 128 KB
  int t = threadIdx.x;
  int bidx = blockIdx.x;
  if (bidx >= NT) {
    if (MODE == 0) {
      // ---- GA q/k projection: 2 tasks (h, 256-row chunk) per block ----
      ushort* WQ = LDS;                  // [64][72]
      ushort* WK = LDS + 4608;
      for (int i = t; i < 4096; i += 512) {
        int d = i >> 6, c = i & 63;
        __hip_bfloat16 q = __float2bfloat16(gwq[i]);
        __hip_bfloat16 k = __float2bfloat16(gwk[i]);
        WQ[d*72 + c] = *(ushort*)&q;
        WK[d*72 + c] = *(ushort*)&k;
      }
      __syncthreads();
      int task = (bidx - 144)*2 + (t >> 8);
      int h  = task >> 4;
      int r0 = (task & 15) * 256;
      int t2 = t & 255;
      int lane = t2 & 63, w = t2 >> 6;
      int lrow = lane & 15, lhi = lane >> 4;
      const ushort* Ag2 = (const ushort*)lnga;
      bf16x8 a[4][2];
      #pragma unroll
      for (int i = 0; i < 4; ++i)
        #pragma unroll
        for (int ks = 0; ks < 2; ++ks)
          a[i][ks] = *(const bf16x8*)(Ag2 + (size_t)(r0 + w*64 + i*16 + lrow)*DM + h*64 + ks*32 + lhi*8);
      int b = r0 >> 9;
      #pragma unroll
      for (int qk = 0; qk < 2; ++qk) {
        const ushort* Wm = qk ? WK : WQ;
        const float* bias = qk ? gbk : gbq;
        float* Og = qk ? Kg : Qg;
        bf16x8 bf[4][2];
        #pragma unroll
        for (int j = 0; j < 4; ++j)
          #pragma unroll
          for (int ks = 0; ks < 2; ++ks)
            bf[j][ks] = *(const bf16x8*)&Wm[(j*16 + lrow)*72 + ks*32 + lhi*8];
        f32x4 acc[4][4] = {};
        #pragma unroll
        for (int i = 0; i < 4; ++i)
          #pragma unroll
          for (int j = 0; j < 4; ++j) {
            acc[i][j] = __builtin_amdgcn_mfma_f32_16x16x32_bf16(a[i][0], bf[j][0], acc[i][j], 0, 0, 0);
            acc[i][j] = __builtin_amdgcn_mfma_f32_16x16x32_bf16(a[i][1], bf[j][1], acc[i][j], 0, 0, 0);
          }
        #pragma unroll
        for (int i = 0; i < 4; ++i) {
          int rowb = r0 + w*64 + i*16 + lhi*4;
          #pragma unroll
          for (int j = 0; j < 4; ++j) {
            int d = j*16 + lrow;
            float bv = bias[d];
            #pragma unroll
            for (int r = 0; r < 4; ++r) {
              int sIdx = (rowb + r) & 511;
              Og[(((size_t)b*HEADS + h)*SEQ + sIdx)*DKH + d] = acc[i][j][r] + bv;
            }
          }
        }
      }
    } else {
      // ---- gb writer: 4 q-rows per block ----
      int base = (MODE == 1) ? 16384 : 32768;
      int row = base + (bidx - NT)*4 + (t >> 7);
      gb_rows_512(row, t, nsWS, cumWS, prior, gp, bp);
    }
    return;
  }
  int lane = t & 63, w = t >> 6;
  int rin = lane >> 3, gr = lane & 7;
  int lrow = lane & 15, lhi = lane >> 4;
  // ---- XCD-footprint-shaped tile mapping (bijective) ----
  int z = 0, mtile, ntile;
  if (MODE == 0) {
    int tile = (bidx & 7)*18 + (bidx >> 3);
    mtile = tile / TN; ntile = tile % TN;
  } else if (MODE == 1) {
    int xq = bidx & 7, i = bidx >> 3;
    mtile = (xq & 3)*4 + i/6;
    ntile = (xq >> 2)*6 + i%6;
  } else {
    int xq = bidx & 7, i = bidx >> 3;
    z = xq >> 1;
    int tl = (xq & 1)*24 + i;
    mtile = tl / 3; ntile = tl % 3;
  }
  int m0 = mtile * 256;
  int n0 = ntile * 256;
  int kOff = (MODE == 2) ? z * 768 : 0;
  if (MODE == 2) C += (size_t)z * MROWS * 768;
  int wr = w >> 2, wc = w & 3;
  const ushort* Ag = (const ushort*)A;
  const ushort* Bg = (const ushort*)B;
  f32x4 acc[8][4] = {};
  int cs = (gr ^ rin) * 8;        // pre-swizzled global source column granule
  // quarter-granular stagers (1 gload per wave per call); dest LDS linear
  auto STAGE_A = [&](int p, int kt, int q) {
    int k0 = kOff + kt*64;
    int rr = q*64 + w*8 + rin;
    gload_lds16(Ag + (size_t)(m0 + rr)*LDAB + k0 + cs, &LDS[p*16384 + (q*64 + w*8)*64]);
  };
  auto STAGE_B = [&](int p, int kt, int q) {
    int k0 = kOff + kt*64;
    int rr = q*64 + w*8 + rin;
    gload_lds16(Bg + (size_t)(n0 + rr)*LDAB + k0 + cs, &LDS[32768 + p*16384 + (q*64 + w*8)*64]);
  };
  auto STAGE8 = [&](int p, int kt) {
    #pragma unroll
    for (int q = 0; q < 4; ++q) { STAGE_A(p, kt, q); STAGE_B(p, kt, q); }
  };
  const int nt = 12;                            // K = 768, BK = 64
  STAGE8(0, 0);
  STAGE8(1, 1);
  asm volatile("s_waitcnt vmcnt(8)" ::: "memory");   // tile 0 landed (tile 1 in flight)
  __builtin_amdgcn_s_barrier();
  int p = 0;
  for (int kt = 0; kt < nt; ++kt) {
    const ushort* Ar = &LDS[p*16384];
    const ushort* Br = &LDS[32768 + p*16384];
    int sw0 = (lhi ^ (lrow & 7)) * 8;           // ks=0 granule (swizzled read)
    int sw1 = ((4 + lhi) ^ (lrow & 7)) * 8;     // ks=1 granule
    bf16x8 aF[8][2], bF[4][2];
    // ---- Phase A: read a(i0-3)+all b; MFMA i0-3 x ks0 -------------------------------
    #pragma unroll
    for (int i = 0; i < 4; ++i) {
      aF[i][0] = *(const bf16x8*)&Ar[(wr*128 + i*16 + lrow)*64 + sw0];
      aF[i][1] = *(const bf16x8*)&Ar[(wr*128 + i*16 + lrow)*64 + sw1];
    }
    #pragma unroll
    for (int j = 0; j < 4; ++j) {
      bF[j][0] = *(const bf16x8*)&Br[(wc*64 + j*16 + lrow)*64 + sw0];
      bF[j][1] = *(const bf16x8*)&Br[(wc*64 + j*16 + lrow)*64 + sw1];
    }
    asm volatile("s_waitcnt lgkmcnt(0)" ::: "memory");
    __builtin_amdgcn_sched_barrier(0);
    __builtin_amdgcn_s_setprio(1);
    #pragma unroll
    for (int i = 0; i < 4; ++i)
      #pragma unroll
      for (int j = 0; j < 4; ++j)
        acc[i][j] = __builtin_amdgcn_mfma_f32_16x16x32_bf16(aF[i][0], bF[j][0], acc[i][j], 0, 0, 0);
    __builtin_amdgcn_s_setprio(0);
    __builtin_amdgcn_s_barrier();               // B rows + A rows {0-63,128-191} free
    // ---- Phase B: read a(i4-7); stage B q0,q1; MFMA i0-3 x ks1 ----------------------
    #pragma unroll
    for (int i = 4; i < 8; ++i) {
      aF[i][0] = *(const bf16x8*)&Ar[(wr*128 + i*16 + lrow)*64 + sw0];
      aF[i][1] = *(const bf16x8*)&Ar[(wr*128 + i*16 + lrow)*64 + sw1];
    }
    if (kt + 2 < nt) { STAGE_B(p, kt+2, 0); STAGE_B(p, kt+2, 1); }
    __builtin_amdgcn_s_setprio(1);
    #pragma unroll
    for (int i = 0; i < 4; ++i)
      #pragma unroll
      for (int j = 0; j < 4; ++j)
        acc[i][j] = __builtin_amdgcn_mfma_f32_16x16x32_bf16(aF[i][1], bF[j][1], acc[i][j], 0, 0, 0);
    __builtin_amdgcn_s_setprio(0);
    asm volatile("s_waitcnt lgkmcnt(0)" ::: "memory");  // a(i4-7) reads executed
    __builtin_amdgcn_sched_barrier(0);
    __builtin_amdgcn_s_barrier();               // A rows {64-127,192-255} free
    // ---- Phase C: stage rest; MFMA i4-7 x ks0 then x ks1 ----------------------------
    if (kt + 2 < nt) { STAGE_B(p, kt+2, 2); STAGE_B(p, kt+2, 3); STAGE_A(p, kt+2, 0); STAGE_A(p, kt+2, 2); }
    __builtin_amdgcn_s_setprio(1);
    #pragma unroll
    for (int i = 4; i < 8; ++i)
      #pragma unroll
      for (int j = 0; j < 4; ++j)
        acc[i][j] = __builtin_amdgcn_mfma_f32_16x16x32_bf16(aF[i][0], bF[j][0], acc[i][j], 0, 0, 0);
    __builtin_amdgcn_s_setprio(0);
    if (kt + 2 < nt) { STAGE_A(p, kt+2, 1); STAGE_A(p, kt+2, 3); }
    __builtin_amdgcn_s_setprio(1);
    #pragma unroll
    for (int i = 4; i < 8; ++i)
      #pragma unroll
      for (int j = 0; j < 4; ++j)
        acc[i][j] = __builtin_amdgcn_mfma_f32_16x16x32_bf16(aF[i][1], bF[j][1], acc[i][j], 0, 0, 0);
    __builtin_amdgcn_s_setprio(0);
    if (kt + 1 < nt) {
      if (kt + 2 < nt) asm volatile("s_waitcnt vmcnt(8)" ::: "memory");  // next tile landed
      else             asm volatile("s_waitcnt vmcnt(0)" ::: "memory");
      __builtin_amdgcn_s_barrier();
    }
    p ^= 1;
  }
  // ---- epilogue ----
  if (MODE == 0 && n0 >= 1536) {
    // V tile: bias + transpose via two-pass LDS bounce -> vT[bh][d][s]
    ushort* T = LDS;                      // [128][264] per pass
    int b = m0 >> 9, s0 = m0 & 511;
    #pragma unroll
    for (int ps = 0; ps < 2; ++ps) {
      if ((wc >> 1) == ps) {
        #pragma unroll
        for (int j = 0; j < 4; ++j) {
          int dl = (wc & 1)*64 + j*16 + lrow;
          float bvv = b2[n0 - 1536 + ps*128 + dl];
          #pragma unroll
          for (int i = 0; i < 8; ++i) {
            #pragma unroll
            for (int r = 0; r < 4; ++r) {
              __hip_bfloat16 hh = __float2bfloat16(acc[i][j][r] + bvv);
              T[dl*264 + wr*128 + i*16 + lhi*4 + r] = *(ushort*)&hh;
            }
          }
        }
      }
      __syncthreads();
      #pragma unroll
      for (int it = 0; it < 8; ++it) {
        int idx = t + 512*it;
        int dl = idx >> 5, sc8 = (idx & 31)*8;
        int dg = n0 - 1536 + ps*128 + dl;
        int h = dg >> 6, dmod = dg & 63;
        bf16x8 vv = *(const bf16x8*)&T[dl*264 + sc8];
        *(bf16x8*)((ushort*)vT + ((size_t)(b*HEADS + h)*64 + dmod)*512 + s0 + sc8) = vv;
      }
      __syncthreads();
    }
    return;
  }
  #pragma unroll
  for (int i = 0; i < 8; ++i) {
    int grow = m0 + wr*128 + i*16 + lhi*4;
    #pragma unroll
    for (int j = 0; j < 4; ++j) {
      int gcol = n0 + wc*64 + j*16 + lrow;
      float bvv;
      if (MODE == 0)      bvv = (gcol < 768) ? b0[gcol] : b1[gcol-768];
      else if (MODE == 1) bvv = b0[gcol];
      else                bvv = 0.f;
      #pragma unroll
      for (int r = 0; r < 4; ++r) {
        float v = acc[i][j][r] + bvv;
        if (MODE == 1) v = fmaxf(v, 0.f);
        C[(size_t)(grow + r)*N + gcol] = __float2bfloat16(v);
      }
    }
  }
}

// ---------------- FFN2 reduce: out += bias + sum of 4 bf16 partials --------------------
__global__ __launch_bounds__(256) void ffn2_reduce_kernel(
    const __hip_bfloat16* __restrict__ p, const float* __restrict__ bias,
    float* __restrict__ out) {
  int gid = blockIdx.x*256 + threadIdx.x;
  size_t i = (size_t)gid*8;
  const ushort* pp = (const ushort*)p;
  float acc[8];
  int col = (int)(i % DM);
  #pragma unroll
  for (int j = 0; j < 8; ++j) acc[j] = bias[col + j];
  #pragma unroll
  for (int s = 0; s < 4; ++s) {
    bf16x8 v = *(const bf16x8*)(pp + (size_t)s*MROWS*DM + i);
    #pragma unroll
    for (int j = 0; j < 8; ++j) acc[j] += b2f((ushort)v[j]);
  }
  float4 o0 = *(const float4*)(out + i);
  float4 o1 = *(const float4*)(out + i + 4);
  o0.x += acc[0]; o0.y += acc[1]; o0.z += acc[2]; o0.w += acc[3];
  o1.x += acc[4]; o1.y += acc[5]; o1.z += acc[6]; o1.w += acc[7];
  *(float4*)(out + i)     = o0;
  *(float4*)(out + i + 4) = o1;
}

// ---------------- residual add + LN (wave-per-row) -------------------------------------
__global__ __launch_bounds__(256) void ln_res_kernel(
    const float* __restrict__ x, const __hip_bfloat16* __restrict__ a, float* __restrict__ xs,
    const float* __restrict__ g, const float* __restrict__ b, __hip_bfloat16* __restrict__ o) {
  int t = threadIdx.x;
  int lane = t & 63, w = t >> 6;
  int row = blockIdx.x*4 + w;
  size_t base = (size_t)row * DM;
  const ushort* ab = (const ushort*)a;
  float v[12]; float s = 0.f, s2 = 0.f;
  #pragma unroll
  for (int i = 0; i < 12; ++i) {
    int c = lane + 64*i;
    v[i] = x[base + c] + b2f(ab[base + c]);
    xs[base + c] = v[i];
    s += v[i]; s2 += v[i]*v[i];
  }
  #pragma unroll
  for (int off = 1; off < 64; off <<= 1) {
    s  += __shfl_xor(s,  off, 64);
    s2 += __shfl_xor(s2, off, 64);
  }
  float mean = s * (1.f/DM);
  float rstd = rsqrtf(s2 * (1.f/DM) - mean*mean + 1e-5f);
  #pragma unroll
  for (int i = 0; i < 12; ++i) {
    int c = lane + 64*i;
    o[base + c] = __float2bfloat16((v[i]-mean)*rstd*g[c] + b[c]);
  }
}

// ---------------- MFMA flash attention + gb-writer blocks ------------------------------
__global__ __launch_bounds__(256) void attn_mfma_kernel(
    const __hip_bfloat16* __restrict__ qk, const __hip_bfloat16* __restrict__ vT,
    const float* __restrict__ cumWS, const float* __restrict__ prior,
    __hip_bfloat16* __restrict__ att,
    const float* __restrict__ nsWS, float* __restrict__ gp, float* __restrict__ bp) {
  __shared__ ushort Ps[4][16][72];
  int t = threadIdx.x;
  int bidx = blockIdx.x;
  if (bidx >= 768) {
    int row = (bidx - 768)*4 + (t >> 6);   // rows [0, 16384)
    gb_rows_256(row, t, nsWS, cumWS, prior, gp, bp);
    return;
  }
  int lane = t & 63, wid = t >> 6;
  int tile = (bidx & 7)*96 + (bidx >> 3);
  int qt = tile & 7, bh = tile >> 3;
  int b = bh / HEADS, h = bh % HEADS;
  int lrow = lane & 15, lhi = lane >> 4;
  int qbase = qt*64 + wid*16;
  const ushort* qg = (const ushort*)qk;
  bf16x8 aq[2];
  {
    const ushort* qp = qg + (size_t)(b*SEQ + qbase + lrow)*2304 + h*64 + lhi*8;
    aq[0] = *(const bf16x8*)qp;
    aq[1] = *(const bf16x8*)(qp + 32);
  }
  const float* cum = cumWS + (size_t)bh*SEQ;
  float pr = prior[0];
  float c0 = pr + (1.f - pr)*0.01f;
  int qrow[4]; float cq[4];
  #pragma unroll
  for (int r = 0; r < 4; ++r) { qrow[r] = qbase + lhi*4 + r; cq[r] = cum[qrow[r]]; }
  float lsum[4] = {0.f, 0.f, 0.f, 0.f};
  f32x4 oacc[4] = {};
  const ushort* kg = qg + 768;
  const ushort* vg = (const ushort*)vT;
  for (int kt = 0; kt < 8; ++kt) {
    f32x4 sacc[4] = {};
    #pragma unroll
    for (int j = 0; j < 4; ++j) {
      const ushort* kp = kg + (size_t)(b*SEQ + kt*64 + j*16 + lrow)*2304 + h*64 + lhi*8;
      bf16x8 bk0 = *(const bf16x8*)kp;
      bf16x8 bk1 = *(const bf16x8*)(kp + 32);
      sacc[j] = __builtin_amdgcn_mfma_f32_16x16x32_bf16(aq[0], bk0, sacc[j], 0, 0, 0);
      sacc[j] = __builtin_amdgcn_mfma_f32_16x16x32_bf16(aq[1], bk1, sacc[j], 0, 0, 0);
    }
    float ck[4];
    #pragma unroll
    for (int j = 0; j < 4; ++j) ck[j] = cum[kt*64 + j*16 + lrow];
    #pragma unroll
    for (int j = 0; j < 4; ++j) {
      int kk = kt*64 + j*16 + lrow;
      #pragma unroll
      for (int r = 0; r < 4; ++r) {
        float e = __expf(fminf(sacc[j][r]*0.125f - 16.f, 60.f));
        lsum[r] += e;
        float dd = ck[j] - cq[r];
        float gpv = (kk == qrow[r]) ? c0 : (__expf((kk > qrow[r]) ? dd : -dd) + 1e-4f);
        __hip_bfloat16 pb = __float2bfloat16(e * gpv);
        Ps[wid][lhi*4 + r][j*16 + lrow] = *(ushort*)&pb;
      }
    }
    asm volatile("s_waitcnt lgkmcnt(0)" ::: "memory");
    __builtin_amdgcn_s_setprio(1);
    #pragma unroll
    for (int c = 0; c < 2; ++c) {
      bf16x8 ap = *(const bf16x8*)&Ps[wid][lrow][c*32 + lhi*8];
      #pragma unroll
      for (int dj = 0; dj < 4; ++dj) {
        const ushort* vp = vg + ((size_t)bh*64 + dj*16 + lrow)*512 + kt*64 + c*32 + lhi*8;
        bf16x8 bv = *(const bf16x8*)vp;
        oacc[dj] = __builtin_amdgcn_mfma_f32_16x16x32_bf16(ap, bv, oacc[dj], 0, 0, 0);
      }
    }
    __builtin_amdgcn_s_setprio(0);
  }
  #pragma unroll
  for (int off = 1; off < 16; off <<= 1) {
    #pragma unroll
    for (int r = 0; r < 4; ++r) lsum[r] += __shfl_xor(lsum[r], off, 64);
  }
  float inv[4];
  #pragma unroll
  for (int r = 0; r < 4; ++r) inv[r] = 1.f / lsum[r];
  #pragma unroll
  for (int dj = 0; dj < 4; ++dj) {
    #pragma unroll
    for (int r = 0; r < 4; ++r) {
      float v = oacc[dj][r] * inv[r];
      att[(size_t)(b*SEQ + qbase + lhi*4 + r)*DM + h*64 + dj*16 + lrow] = __float2bfloat16(v);
    }
  }
}

// ======================================================================================
extern "C" void kernel_launch(void* const* d_in, const int* in_sizes, int n_in,
                              void* d_out, int out_size, void* d_ws, size_t ws_size,
                              hipStream_t stream) {
  const float* x      = (const float*)d_in[0];
  const float* prior  = (const float*)d_in[2];
  const float* ga_g   = (const float*)d_in[3];
  const float* ga_b   = (const float*)d_in[4];
  const float* ga_wq  = (const float*)d_in[5];
  const float* ga_bq  = (const float*)d_in[6];
  const float* ga_wk  = (const float*)d_in[7];
  const float* ga_bk  = (const float*)d_in[8];
  const float* sa_wq  = (const float*)d_in[9];
  const float* sa_bq  = (const float*)d_in[10];
  const float* sa_wk  = (const float*)d_in[11];
  const float* sa_bk  = (const float*)d_in[12];
  const float* sa_wv  = (const float*)d_in[13];
  const float* sa_bv  = (const float*)d_in[14];
  const float* ff_w1  = (const float*)d_in[15];
  const float* ff_b1  = (const float*)d_in[16];
  const float* ff_w2  = (const float*)d_in[17];
  const float* ff_b2  = (const float*)d_in[18];
  const float* sl0_g  = (const float*)d_in[19];
  const float* sl0_b  = (const float*)d_in[20];
  const float* sl1_g  = (const float*)d_in[21];
  const float* sl1_b  = (const float*)d_in[22];

  float* out_x  = (float*)d_out;
  float* out_gp = out_x  + (size_t)MROWS*DM;
  float* out_bp = out_gp + (size_t)BH*SEQ*SEQ;

  char* W = (char*)d_ws;
  __hip_bfloat16* ln0    = (__hip_bfloat16*)(W + 0);          // 6.29 MB
  __hip_bfloat16* lnga   = (__hip_bfloat16*)(W + 6291456);    // 6.29 MB
  float* Qg   = (float*)(W + 12582912);                       // 12.58 MB
  float* Kg   = (float*)(W + 25165824);                       // 12.58 MB
  __hip_bfloat16* qkv3   = (__hip_bfloat16*)(W + 37748736);   // 18.87 MB [4096][2304]
  __hip_bfloat16* vT     = (__hip_bfloat16*)(W + 56623104);   // 6.29 MB
  __hip_bfloat16* attbuf = (__hip_bfloat16*)(W + 62914560);   // 6.29 MB
  __hip_bfloat16* ln1    = (__hip_bfloat16*)(W + 69206016);   // 6.29 MB
  __hip_bfloat16* wqkv   = (__hip_bfloat16*)(W + 75497472);   // 3.54 MB
  __hip_bfloat16* w1     = (__hip_bfloat16*)(W + 79036416);   // 4.72 MB
  __hip_bfloat16* w2     = (__hip_bfloat16*)(W + 83755008);   // 4.72 MB
  __hip_bfloat16* hbuf   = (__hip_bfloat16*)(W + 88473600);   // 25.17 MB [4096][3072]
  __hip_bfloat16* parts  = (__hip_bfloat16*)(W + 113639424);  // 25.17 MB (4 x 6.29)
  float* nsWS  = (float*)(W + 138805248);
  float* cumWS = (float*)(W + 139001856);

  // 1. dual pre-norm (both bf16) + weight conversions
  ln_cvt_kernel<<<7360, 256, 0, stream>>>(
      x, sl0_g, sl0_b, ln0, ga_g, ga_b, lnga,
      sa_wq, sa_wk, sa_wv, ff_w1, ff_w2, wqkv, w1, w2);
  // 2. QKV GEMM (V transposed in-epilogue) || GA q/k projection (role-split)
  gemm256_kernel<0><<<240, 512, 0, stream>>>(
      ln0, wqkv, sa_bq, sa_bk, sa_bv, qkv3, vT,
      nullptr, nullptr, nullptr, nullptr, nullptr,
      lnga, ga_wq, ga_bq, ga_wk, ga_bk, Qg, Kg);
  // 3. tridiagonal softmax -> ns + cum
  ga_edges_kernel<<<BH, SEQ, 0, stream>>>(Qg, Kg, prior, nsWS, cumWS);
  // 4. flash attention + writer rows [0,16384)
  attn_mfma_kernel<<<768 + 4096, 256, 0, stream>>>(
      qkv3, vT, cumWS, prior, attbuf, nsWS, out_gp, out_bp);
  // 5. residual + pre-norm for FFN (wave-per-row)
  ln_res_kernel<<<1024, 256, 0, stream>>>(x, attbuf, out_x, sl1_g, sl1_b, ln1);
  // 6. FFN1 GEMM + writer rows [16384,32768)
  gemm256_kernel<1><<<192 + 4096, 512, 0, stream>>>(
      ln1, w1, ff_b1, nullptr, nullptr, hbuf, nullptr,
      nsWS, cumWS, prior, out_gp, out_bp,
      nullptr, nullptr, nullptr, nullptr, nullptr, nullptr, nullptr);
  // 7. FFN2 split-K x4 + writer rows [32768,49152)
  gemm256_kernel<2><<<192 + 4096, 512, 0, stream>>>(
      hbuf, w2, nullptr, nullptr, nullptr, parts, nullptr,
      nsWS, cumWS, prior, out_gp, out_bp,
      nullptr, nullptr, nullptr, nullptr, nullptr, nullptr, nullptr);
  // 8. reduce partials + bias + residual
  ffn2_reduce_kernel<<<1536, 256, 0, stream>>>(parts, ff_b2, out_x);
}